// Round 12
// baseline (395.702 us; speedup 1.0000x reference)
//
#include <hip/hip_runtime.h>
#include <hip/hip_bf16.h>

#define N_NODES 100000
#define N_EDGES 1600000
#define NFEAT   128
#define NGRAPH  256
#define NACT    32
#define ECAP    64
#define OVF_CAP 8192

// ---- two-pass edge partition ----
#define BUCK_SHIFT 9
#define BUCK_NODES 512
#define NBUCK ((N_NODES + BUCK_NODES - 1) / BUCK_NODES)   // 196
#define SEGCAP 10240          // mean 8192, +22 sigma
#define CHUNK 4096            // edges per pass-1 block (R9-measured best)
#define NBLK1 ((N_EDGES + CHUNK - 1) / CHUNK)             // 391
#define BIN_NODES 128         // pass-2 nodes per block
#define NBLK2 ((N_NODES + BIN_NODES - 1) / BIN_NODES)     // 782

typedef __attribute__((ext_vector_type(8))) short bf16x8;
typedef __attribute__((ext_vector_type(4))) float f32x4;

__device__ inline unsigned short f2bf(float f) {
  __hip_bfloat16 b = __float2bfloat16(f);
  return *reinterpret_cast<unsigned short*>(&b);
}
__device__ inline float2 bfu2f(unsigned u) {
  __hip_bfloat162 t = *reinterpret_cast<__hip_bfloat162*>(&u);
  return __bfloat1622float2(t);
}

// ---- pass 1: block-local bucket sort in LDS, dense segment flush ----
__global__ __launch_bounds__(256) void edgepart_kernel(const int* __restrict__ src,
                                                       const int* __restrict__ dst,
                                                       int* __restrict__ bucket_cursor,
                                                       int2* __restrict__ seg,
                                                       int* __restrict__ cnt,
                                                       int* __restrict__ ovf_cnt,
                                                       int* __restrict__ ovf) {
  __shared__ int2 stage[CHUNK];               // 32 KB
  __shared__ int hist[NBUCK], offs[NBUCK], cursor[NBUCK], gbase[NBUCK];
  __shared__ int sc[256];
  int tid = threadIdx.x;
  int e0 = blockIdx.x * CHUNK;
  int m = N_EDGES - e0; if (m > CHUNK) m = CHUNK;

  for (int i = tid; i < NBUCK; i += 256) hist[i] = 0;
  __syncthreads();

  for (int i = tid; i < m; i += 256)
    atomicAdd(&hist[dst[e0 + i] >> BUCK_SHIFT], 1);
  __syncthreads();

  sc[tid] = (tid < NBUCK) ? hist[tid] : 0;
  __syncthreads();
  for (int ofs = 1; ofs < 256; ofs <<= 1) {
    int t = (tid >= ofs) ? sc[tid - ofs] : 0;
    __syncthreads();
    sc[tid] += t;
    __syncthreads();
  }
  if (tid < NBUCK) {
    int o = tid ? sc[tid - 1] : 0;
    offs[tid] = o;
    cursor[tid] = o;
    gbase[tid] = hist[tid] ? atomicAdd(&bucket_cursor[tid], hist[tid]) : 0;
  }
  __syncthreads();

  for (int i = tid; i < m; i += 256) {
    int2 p = make_int2(src[e0 + i], dst[e0 + i]);
    int pos = atomicAdd(&cursor[p.y >> BUCK_SHIFT], 1);
    stage[pos] = p;
  }
  __syncthreads();

  for (int i = tid; i < m; i += 256) {
    int2 p = stage[i];
    int bd = p.y >> BUCK_SHIFT;
    int gpos = gbase[bd] + (i - offs[bd]);
    if (gpos < SEGCAP) {
      seg[(size_t)bd * SEGCAP + gpos] = p;
    } else {                                // ~never: count + defer to agg ovf fixup
      atomicAdd(&cnt[p.y], 1);
      int o = atomicAdd(ovf_cnt, 1);
      if (o < OVF_CAP) { ovf[2 * o] = p.x; ovf[2 * o + 1] = p.y; }
    }
  }
}

// ---- pass 2: per-128-node elist build in LDS, dense writeback (+dinv fused) ----
__global__ __launch_bounds__(256) void binbuild_kernel(const int2* __restrict__ seg,
                                                       const int* __restrict__ bucket_cursor,
                                                       int* __restrict__ cnt,
                                                       float* __restrict__ dinv,
                                                       int* __restrict__ elist,
                                                       int* __restrict__ ovf_cnt,
                                                       int* __restrict__ ovf) {
  __shared__ int lcnt[BIN_NODES];
  __shared__ int lel[BIN_NODES * ECAP];     // 32 KB
  int tid = threadIdx.x;
  int n0 = blockIdx.x * BIN_NODES;
  int pb = n0 >> BUCK_SHIFT;
  if (tid < BIN_NODES) lcnt[tid] = 0;
  __syncthreads();
  int m = bucket_cursor[pb]; if (m > SEGCAP) m = SEGCAP;
  const int2* s = seg + (size_t)pb * SEGCAP;
  for (int e = tid; e < m; e += 256) {
    int2 p = s[e];
    unsigned ln = (unsigned)(p.y - n0);
    if (ln < (unsigned)BIN_NODES) {
      int pos = atomicAdd(&lcnt[ln], 1);
      if (pos < ECAP) {
        lel[(ln << 6) + pos] = p.x;
      } else {                              // high-degree node: agg ovf fixup
        int o = atomicAdd(ovf_cnt, 1);
        if (o < OVF_CAP) { ovf[2 * o] = p.x; ovf[2 * o + 1] = p.y; }
      }
    }
  }
  __syncthreads();
  if (tid < BIN_NODES) {
    int n = n0 + tid;
    if (n < N_NODES) {
      int tot = cnt[n] + lcnt[tid];          // cnt[n]: pass-1 ovf edges only
      cnt[n] = tot;                          // safe: block owns node range
      dinv[n] = rsqrtf((float)tot + 1.0f);   // fused dinv
    }
  }
  int4* gel = (int4*)(elist + (size_t)n0 * ECAP);
  const int4* lel4 = (const int4*)lel;
  for (int i = tid; i < BIN_NODES * ECAP / 4; i += 256) gel[i] = lel4[i];
}

// ---- x(f32)->bf16 prepass + Wt[n][k]=bf16(W[k][n]) for both layers, one launch
#define CVT_XBLK (N_NODES * NFEAT / 8 / 256)   // 6250: 8 floats/thread
__global__ __launch_bounds__(256) void cvt_kernel(const float* __restrict__ x,
                                                  const float* __restrict__ W1,
                                                  const float* __restrict__ W2,
                                                  unsigned* __restrict__ Xbf,
                                                  unsigned short* __restrict__ Wt1,
                                                  unsigned short* __restrict__ Wt2) {
  int b = blockIdx.x;
  if (b < CVT_XBLK) {
    int idx = b * 256 + threadIdx.x;          // 8 floats per thread
    const float4* x4 = (const float4*)x + (size_t)idx * 2;
    float4 a0 = x4[0], a1 = x4[1];
    uint4 r;
    r.x = ((unsigned)f2bf(a0.y) << 16) | f2bf(a0.x);
    r.y = ((unsigned)f2bf(a0.w) << 16) | f2bf(a0.z);
    r.z = ((unsigned)f2bf(a1.y) << 16) | f2bf(a1.x);
    r.w = ((unsigned)f2bf(a1.w) << 16) | f2bf(a1.z);
    ((uint4*)Xbf)[idx] = r;
  } else {
    int i = (b - CVT_XBLK) * 256 + threadIdx.x;  // 32768 weight elems
    int which = i >> 14;
    int idx = i & 16383;
    int n = idx >> 7, k = idx & 127;
    if (which == 0) Wt1[n * NFEAT + k] = f2bf(W1[k * NFEAT + n]);
    else            Wt2[n * NFEAT + k] = f2bf(W2[k * NFEAT + n]);
  }
}

// ---------------- GEMM: C(bf16) = (relu?)A(bf16) @ W via MFMA ------------
// Operands swapped: A-operand = W-fragment, B-operand = node-fragment, so
// lane (q,r) holds 4 CONTIGUOUS features of node m0+r -> coalesced uint2 stores.
__global__ __launch_bounds__(256) void gemm_kernel(const unsigned short* __restrict__ A,
                                                   const unsigned short* __restrict__ Wt,
                                                   unsigned short* __restrict__ C,
                                                   int relu_in) {
  int tid = threadIdx.x;
  int wave = tid >> 6, lane = tid & 63;
  int q = lane >> 4, r = lane & 15;
  int m0 = blockIdx.x * 64 + wave * 16;
  int arow = m0 + r; if (arow > N_NODES - 1) arow = N_NODES - 1;
  const unsigned short* Arow = A + (size_t)arow * NFEAT;

  f32x4 acc[8];
  #pragma unroll
  for (int t = 0; t < 8; ++t) acc[t] = (f32x4){0.f, 0.f, 0.f, 0.f};

  #pragma unroll
  for (int s = 0; s < 4; ++s) {
    int k0 = s * 32 + q * 8;
    bf16x8 xf = *(const bf16x8*)(Arow + k0);   // direct 16B bf16 load
    if (relu_in) {
      #pragma unroll
      for (int i = 0; i < 8; ++i)              // relu: bf16 sign bit == short sign
        xf[i] = (short)(xf[i] < (short)0 ? (short)0 : xf[i]);
    }
    #pragma unroll
    for (int t = 0; t < 8; ++t) {
      bf16x8 wf = *(const bf16x8*)(Wt + (size_t)(t * 16 + r) * NFEAT + k0);
      acc[t] = __builtin_amdgcn_mfma_f32_16x16x32_bf16(wf, xf, acc[t], 0, 0, 0);
    }
  }
  int node = m0 + r;
  if (node < N_NODES) {
    uint2* Crow = (uint2*)(C + (size_t)node * NFEAT);
    #pragma unroll
    for (int t = 0; t < 8; ++t) {
      uint2 v;
      v.x = ((unsigned)f2bf(acc[t][1]) << 16) | f2bf(acc[t][0]);
      v.y = ((unsigned)f2bf(acc[t][3]) << 16) | f2bf(acc[t][2]);
      Crow[t * 4 + q] = v;    // features [t*16+q*4, +4)
    }
  }
}

// ---------------- gather aggregation: HALF-WAVE per node (at the random-gather
// wall ~64us) + fused ovf fixup (fp32, pre-rounding) ----------
__global__ __launch_bounds__(256) void agg_kernel(const uint2* __restrict__ h2,
                                                  const int* __restrict__ elist,
                                                  const int* __restrict__ cnt,
                                                  const float* __restrict__ dinv,
                                                  const float* __restrict__ bias,
                                                  const int* __restrict__ ovf_cnt,
                                                  const int* __restrict__ ovf,
                                                  uint2* __restrict__ out) {
  int wid = (blockIdx.x * 256 + threadIdx.x) >> 6;
  int lane = threadIdx.x & 63;
  int hl = lane & 31;
  int n = wid * 2 + (lane >> 5);
  if (n >= N_NODES) return;
  float dn = dinv[n];
  int c = cnt[n]; c = (c > ECAP) ? ECAP : c;
  const int* el = elist + (size_t)n * ECAP;

  int   s0 = (hl < c)      ? el[hl]      : n;
  float w0 = (hl < c)      ? dinv[s0] * dn : 0.f;
  int   s1 = (hl + 32 < c) ? el[hl + 32] : n;
  float w1 = (hl + 32 < c) ? dinv[s1] * dn : 0.f;

  int cA = __shfl(c, 0), cB = __shfl(c, 32);
  int cmax = cA > cB ? cA : cB;

  uint2 hv = h2[(size_t)n * 32 + hl];
  float2 vlo = bfu2f(hv.x), vhi = bfu2f(hv.y);
  float sw = dn * dn;
  float a0 = sw * vlo.x, a1 = sw * vlo.y, a2 = sw * vhi.x, a3 = sw * vhi.y;

  int e1 = cmax < 32 ? cmax : 32;
  int j = 0;
  for (; j + 8 <= e1; j += 8) {
    uint2 pv[8]; float w[8];
    #pragma unroll
    for (int u = 0; u < 8; ++u) {
      int s = __shfl(s0, j + u, 32);
      w[u] = __shfl(w0, j + u, 32);
      pv[u] = h2[(size_t)s * 32 + hl];
    }
    #pragma unroll
    for (int u = 0; u < 8; ++u) {
      float2 lo = bfu2f(pv[u].x), hi = bfu2f(pv[u].y);
      a0 = fmaf(w[u], lo.x, a0); a1 = fmaf(w[u], lo.y, a1);
      a2 = fmaf(w[u], hi.x, a2); a3 = fmaf(w[u], hi.y, a3);
    }
  }
  for (; j < e1; ++j) {
    int s = __shfl(s0, j, 32);
    float w = __shfl(w0, j, 32);
    uint2 pv = h2[(size_t)s * 32 + hl];
    float2 lo = bfu2f(pv.x), hi = bfu2f(pv.y);
    a0 = fmaf(w, lo.x, a0); a1 = fmaf(w, lo.y, a1);
    a2 = fmaf(w, hi.x, a2); a3 = fmaf(w, hi.y, a3);
  }
  if (cmax > 32) {
    j = 32;
    for (; j + 8 <= cmax; j += 8) {
      uint2 pv[8]; float w[8];
      #pragma unroll
      for (int u = 0; u < 8; ++u) {
        int s = __shfl(s1, j - 32 + u, 32);
        w[u] = __shfl(w1, j - 32 + u, 32);
        pv[u] = h2[(size_t)s * 32 + hl];
      }
      #pragma unroll
      for (int u = 0; u < 8; ++u) {
        float2 lo = bfu2f(pv[u].x), hi = bfu2f(pv[u].y);
        a0 = fmaf(w[u], lo.x, a0); a1 = fmaf(w[u], lo.y, a1);
        a2 = fmaf(w[u], hi.x, a2); a3 = fmaf(w[u], hi.y, a3);
      }
    }
    for (; j < cmax; ++j) {
      int s = __shfl(s1, j - 32, 32);
      float w = __shfl(w1, j - 32, 32);
      uint2 pv = h2[(size_t)s * 32 + hl];
      float2 lo = bfu2f(pv.x), hi = bfu2f(pv.y);
      a0 = fmaf(w, lo.x, a0); a1 = fmaf(w, lo.y, a1);
      a2 = fmaf(w, hi.x, a2); a3 = fmaf(w, hi.y, a3);
    }
  }

  // ovf fixup in fp32 before rounding (m == 0 on this input: one load + exit)
  int m = *ovf_cnt; if (m > OVF_CAP) m = OVF_CAP;
  for (int p = 0; p < m; ++p) {
    int s = ovf[2 * p], d = ovf[2 * p + 1];
    if (d == n) {
      float w = dinv[s] * dn;
      uint2 pv = h2[(size_t)s * 32 + hl];
      float2 lo = bfu2f(pv.x), hi = bfu2f(pv.y);
      a0 = fmaf(w, lo.x, a0); a1 = fmaf(w, lo.y, a1);
      a2 = fmaf(w, hi.x, a2); a3 = fmaf(w, hi.y, a3);
    }
  }

  float4 b4 = ((const float4*)bias)[hl];
  uint2 r;
  r.x = ((unsigned)f2bf(a1 + b4.y) << 16) | f2bf(a0 + b4.x);
  r.y = ((unsigned)f2bf(a3 + b4.w) << 16) | f2bf(a2 + b4.z);
  out[(size_t)n * 32 + hl] = r;
}

// ---------------- fused pool + MLP head: one block per graph ----------------
// Thread t owns feature t. Sums relu(h[n][t]) over the graph's node range
// (batch is sorted; range via binary search), then the two small GEMVs.
__global__ __launch_bounds__(128) void poolmlp_kernel(const unsigned short* __restrict__ h,
                                                      const int* __restrict__ batch,
                                                      const float* __restrict__ Wl1,
                                                      const float* __restrict__ bl1,
                                                      const float* __restrict__ Wl2,
                                                      const float* __restrict__ bl2,
                                                      float* __restrict__ out) {
  __shared__ float gr[NFEAT];
  __shared__ float t1[NFEAT];
  int g = blockIdx.x, t = threadIdx.x;
  int lo = 0, hi = N_NODES;                    // redundant per-thread search (uniform)
  while (lo < hi) { int mid = (lo + hi) >> 1; if (batch[mid] < g) lo = mid + 1; else hi = mid; }
  int lo2 = lo, hi2 = N_NODES;
  while (lo2 < hi2) { int mid = (lo2 + hi2) >> 1; if (batch[mid] < g + 1) lo2 = mid + 1; else hi2 = mid; }
  float sum = 0.f;
  int n = lo;
  for (; n + 4 <= lo2; n += 4) {
    unsigned short v0 = h[(size_t)(n + 0) * NFEAT + t];
    unsigned short v1 = h[(size_t)(n + 1) * NFEAT + t];
    unsigned short v2 = h[(size_t)(n + 2) * NFEAT + t];
    unsigned short v3 = h[(size_t)(n + 3) * NFEAT + t];
    float f0 = bfu2f((unsigned)v0 << 16).y;    // bf16 in high half -> f32
    float f1 = bfu2f((unsigned)v1 << 16).y;
    float f2 = bfu2f((unsigned)v2 << 16).y;
    float f3 = bfu2f((unsigned)v3 << 16).y;
    sum += fmaxf(f0, 0.f) + fmaxf(f1, 0.f) + fmaxf(f2, 0.f) + fmaxf(f3, 0.f);
  }
  for (; n < lo2; ++n) {
    unsigned short v = h[(size_t)n * NFEAT + t];
    sum += fmaxf(bfu2f((unsigned)v << 16).y, 0.f);
  }
  gr[t] = sum / fmaxf((float)(lo2 - lo), 1.0f);
  __syncthreads();
  float acc = bl1[t];
  for (int k = 0; k < NFEAT; ++k) acc = fmaf(gr[k], Wl1[k * NFEAT + t], acc);
  t1[t] = fmaxf(acc, 0.f);
  __syncthreads();
  if (t < NACT) {
    float a2 = bl2[t];
    for (int k = 0; k < NFEAT; ++k) a2 = fmaf(t1[k], Wl2[k * NACT + t], a2);
    out[g * NACT + t] = a2;
  }
}

extern "C" void kernel_launch(void* const* d_in, const int* in_sizes, int n_in,
                              void* d_out, int out_size, void* d_ws, size_t ws_size,
                              hipStream_t stream) {
  const float* x    = (const float*)d_in[0];
  const int*   ei   = (const int*)d_in[1];
  const int*   batch= (const int*)d_in[2];
  const float* W1   = (const float*)d_in[3];
  const float* b1   = (const float*)d_in[4];
  const float* W2   = (const float*)d_in[5];
  const float* b2   = (const float*)d_in[6];
  const float* Wl1  = (const float*)d_in[7];
  const float* bl1  = (const float*)d_in[8];
  const float* Wl2  = (const float*)d_in[9];
  const float* bl2  = (const float*)d_in[10];
  float* out = (float*)d_out;

  const int* srcp = ei;            // edge_index[0]
  const int* dstp = ei + N_EDGES;  // edge_index[1]

  char* base = (char*)d_ws;
  size_t off = 0;
  auto alloc = [&](size_t bytes) -> void* {
    void* p = base + off;
    off += (bytes + 511) & ~(size_t)511;
    return p;
  };
  int*   cnt     = (int*)alloc((size_t)N_NODES * 4);
  int*   ovfc    = (int*)alloc(4);
  int*   bucket_cursor = (int*)alloc((size_t)NBUCK * 4);
  size_t zspan   = off;  // everything above must start zeroed
  float* dinv    = (float*)alloc((size_t)N_NODES * 4);
  int*   elist   = (int*)alloc((size_t)NBLK2 * BIN_NODES * ECAP * 4); // padded
  int*   ovf     = (int*)alloc((size_t)OVF_CAP * 2 * 4);
  int2*  seg     = (int2*)alloc((size_t)NBUCK * SEGCAP * 8);          // 16 MB
  unsigned short* Wt1 = (unsigned short*)alloc((size_t)NFEAT * NFEAT * 2);
  unsigned short* Wt2 = (unsigned short*)alloc((size_t)NFEAT * NFEAT * 2);
  unsigned* Xbf  = (unsigned*)alloc((size_t)N_NODES * NFEAT * 2);     // bf16 x
  unsigned short* A = (unsigned short*)alloc((size_t)N_NODES * NFEAT * 2); // bf16
  unsigned short* B = (unsigned short*)alloc((size_t)N_NODES * NFEAT * 2); // bf16

  hipMemsetAsync(d_ws, 0, zspan, stream);

  const int GB = (N_NODES + 63) / 64;     // 1563 gemm blocks
  const int AB = (N_NODES + 7) / 8;       // 12500 agg blocks (8 nodes/block)

  edgepart_kernel<<<NBLK1, 256, 0, stream>>>(srcp, dstp, bucket_cursor, seg, cnt, ovfc, ovf);
  binbuild_kernel<<<NBLK2, 256, 0, stream>>>(seg, bucket_cursor, cnt, dinv, elist, ovfc, ovf);
  cvt_kernel<<<CVT_XBLK + 2 * NFEAT * NFEAT / 256, 256, 0, stream>>>(x, W1, W2, Xbf, Wt1, Wt2);

  // layer 1: A = x @ W1 ; B = agg(A) + selfloop + b1 (relu deferred to gemm2)
  gemm_kernel<<<GB, 256, 0, stream>>>((const unsigned short*)Xbf, Wt1, A, 0);
  agg_kernel<<<AB, 256, 0, stream>>>((const uint2*)A, elist, cnt, dinv, b1, ovfc, ovf, (uint2*)B);

  // layer 2: A = relu(B) @ W2 ; B = agg(A) + selfloop + b2 (relu at poolmlp)
  gemm_kernel<<<GB, 256, 0, stream>>>(B, Wt2, A, 1);
  agg_kernel<<<AB, 256, 0, stream>>>((const uint2*)A, elist, cnt, dinv, b2, ovfc, ovf, (uint2*)B);

  // fused pool + head
  poolmlp_kernel<<<NGRAPH, 128, 0, stream>>>(B, batch, Wl1, bl1, Wl2, bl2, out);
}

// Round 13
// 362.091 us; speedup vs baseline: 1.0928x; 1.0928x over previous
//
#include <hip/hip_runtime.h>
#include <hip/hip_bf16.h>

#define N_NODES 100000
#define N_EDGES 1600000
#define NFEAT   128
#define NGRAPH  256
#define NACT    32
#define ECAP    64
#define OVF_CAP 8192

// ---- two-pass edge partition ----
#define BUCK_SHIFT 9
#define BUCK_NODES 512
#define NBUCK ((N_NODES + BUCK_NODES - 1) / BUCK_NODES)   // 196
#define SEGCAP 10240          // mean 8192, +22 sigma
#define CHUNK 4096            // edges per pass-1 block (R9-measured best)
#define NBLK1 ((N_EDGES + CHUNK - 1) / CHUNK)             // 391
#define BIN_NODES 128         // pass-2 nodes per block
#define NBLK2 ((N_NODES + BIN_NODES - 1) / BIN_NODES)     // 782
#define GB ((N_NODES + 63) / 64)                          // 1563 gemm blocks
#define WTBLK (2 * NFEAT * NFEAT / 256)                   // 128 wt blocks

typedef __attribute__((ext_vector_type(8))) short bf16x8;
typedef __attribute__((ext_vector_type(4))) float f32x4;

__device__ inline unsigned short f2bf(float f) {
  __hip_bfloat16 b = __float2bfloat16(f);
  return *reinterpret_cast<unsigned short*>(&b);
}
__device__ inline float2 bfu2f(unsigned u) {
  __hip_bfloat162 t = *reinterpret_cast<__hip_bfloat162*>(&u);
  return __bfloat1622float2(t);
}

// ---- launch 1: edgepart (blocks [0,NBLK1)) UNION wt transpose (rest) ----
// Independent workloads share one dispatch to cut launch/drain overhead.
__global__ __launch_bounds__(256) void edgepart_wt_kernel(const int* __restrict__ src,
                                                          const int* __restrict__ dst,
                                                          int* __restrict__ bucket_cursor,
                                                          int2* __restrict__ seg,
                                                          int* __restrict__ cnt,
                                                          int* __restrict__ ovf_cnt,
                                                          int* __restrict__ ovf,
                                                          const float* __restrict__ W1,
                                                          const float* __restrict__ W2,
                                                          unsigned short* __restrict__ Wt1,
                                                          unsigned short* __restrict__ Wt2) {
  __shared__ int2 stage[CHUNK];               // 32 KB
  __shared__ int hist[NBUCK], offs[NBUCK], cursor[NBUCK], gbase[NBUCK];
  __shared__ int sc[256];
  int tid = threadIdx.x;

  if (blockIdx.x >= NBLK1) {                  // ---- wt transpose part ----
    int i = (blockIdx.x - NBLK1) * 256 + tid; // 32768 weight elems
    int which = i >> 14;
    int idx = i & 16383;
    int n = idx >> 7, k = idx & 127;
    if (which == 0) Wt1[n * NFEAT + k] = f2bf(W1[k * NFEAT + n]);
    else            Wt2[n * NFEAT + k] = f2bf(W2[k * NFEAT + n]);
    return;
  }

  // ---- edgepart part ----
  int e0 = blockIdx.x * CHUNK;
  int m = N_EDGES - e0; if (m > CHUNK) m = CHUNK;

  for (int i = tid; i < NBUCK; i += 256) hist[i] = 0;
  __syncthreads();

  for (int i = tid; i < m; i += 256)
    atomicAdd(&hist[dst[e0 + i] >> BUCK_SHIFT], 1);
  __syncthreads();

  sc[tid] = (tid < NBUCK) ? hist[tid] : 0;
  __syncthreads();
  for (int ofs = 1; ofs < 256; ofs <<= 1) {
    int t = (tid >= ofs) ? sc[tid - ofs] : 0;
    __syncthreads();
    sc[tid] += t;
    __syncthreads();
  }
  if (tid < NBUCK) {
    int o = tid ? sc[tid - 1] : 0;
    offs[tid] = o;
    cursor[tid] = o;
    gbase[tid] = hist[tid] ? atomicAdd(&bucket_cursor[tid], hist[tid]) : 0;
  }
  __syncthreads();

  for (int i = tid; i < m; i += 256) {
    int2 p = make_int2(src[e0 + i], dst[e0 + i]);
    int pos = atomicAdd(&cursor[p.y >> BUCK_SHIFT], 1);
    stage[pos] = p;
  }
  __syncthreads();

  for (int i = tid; i < m; i += 256) {
    int2 p = stage[i];
    int bd = p.y >> BUCK_SHIFT;
    int gpos = gbase[bd] + (i - offs[bd]);
    if (gpos < SEGCAP) {
      seg[(size_t)bd * SEGCAP + gpos] = p;
    } else {                                // ~never: count + defer to agg ovf fixup
      atomicAdd(&cnt[p.y], 1);
      int o = atomicAdd(ovf_cnt, 1);
      if (o < OVF_CAP) { ovf[2 * o] = p.x; ovf[2 * o + 1] = p.y; }
    }
  }
}

// ---- launch 2: binbuild (blocks [0,NBLK2)) UNION layer-1 GEMM (rest) ----
// binbuild depends on edgepart (launch 1); gemm1 depends on wt (launch 1);
// mutually independent -> one dispatch, MFMA overlaps LDS-atomic work.
__global__ __launch_bounds__(256) void binbuild_gemm_kernel(const int2* __restrict__ seg,
                                                            const int* __restrict__ bucket_cursor,
                                                            int* __restrict__ cnt,
                                                            float* __restrict__ dinv,
                                                            int* __restrict__ elist,
                                                            int* __restrict__ ovf_cnt,
                                                            int* __restrict__ ovf,
                                                            const float* __restrict__ x,
                                                            const unsigned short* __restrict__ Wt,
                                                            unsigned short* __restrict__ C) {
  __shared__ int lcnt[BIN_NODES];
  __shared__ int lel[BIN_NODES * ECAP];     // 32 KB
  int tid = threadIdx.x;

  if (blockIdx.x >= NBLK2) {                // ---- gemm1: C(bf16) = x(f32) @ W1 ----
    int bid = blockIdx.x - NBLK2;
    int wave = tid >> 6, lane = tid & 63;
    int q = lane >> 4, r = lane & 15;
    int m0 = bid * 64 + wave * 16;
    int arow = m0 + r; if (arow > N_NODES - 1) arow = N_NODES - 1;
    const float* Arow = x + (size_t)arow * NFEAT;

    f32x4 acc[8];
    #pragma unroll
    for (int t = 0; t < 8; ++t) acc[t] = (f32x4){0.f, 0.f, 0.f, 0.f};

    #pragma unroll
    for (int s = 0; s < 4; ++s) {
      int k0 = s * 32 + q * 8;
      float4 a0 = *(const float4*)(Arow + k0);
      float4 a1 = *(const float4*)(Arow + k0 + 4);
      bf16x8 xf;
      xf[0] = (short)f2bf(a0.x); xf[1] = (short)f2bf(a0.y);
      xf[2] = (short)f2bf(a0.z); xf[3] = (short)f2bf(a0.w);
      xf[4] = (short)f2bf(a1.x); xf[5] = (short)f2bf(a1.y);
      xf[6] = (short)f2bf(a1.z); xf[7] = (short)f2bf(a1.w);
      #pragma unroll
      for (int t = 0; t < 8; ++t) {
        bf16x8 wf = *(const bf16x8*)(Wt + (size_t)(t * 16 + r) * NFEAT + k0);
        acc[t] = __builtin_amdgcn_mfma_f32_16x16x32_bf16(wf, xf, acc[t], 0, 0, 0);
      }
    }
    int node = m0 + r;
    if (node < N_NODES) {
      uint2* Crow = (uint2*)(C + (size_t)node * NFEAT);
      #pragma unroll
      for (int t = 0; t < 8; ++t) {
        uint2 v;
        v.x = ((unsigned)f2bf(acc[t][1]) << 16) | f2bf(acc[t][0]);
        v.y = ((unsigned)f2bf(acc[t][3]) << 16) | f2bf(acc[t][2]);
        Crow[t * 4 + q] = v;    // features [t*16+q*4, +4)
      }
    }
    return;
  }

  // ---- binbuild part ----
  int n0 = blockIdx.x * BIN_NODES;
  int pb = n0 >> BUCK_SHIFT;
  if (tid < BIN_NODES) lcnt[tid] = 0;
  __syncthreads();
  int m = bucket_cursor[pb]; if (m > SEGCAP) m = SEGCAP;
  const int2* s = seg + (size_t)pb * SEGCAP;
  for (int e = tid; e < m; e += 256) {
    int2 p = s[e];
    unsigned ln = (unsigned)(p.y - n0);
    if (ln < (unsigned)BIN_NODES) {
      int pos = atomicAdd(&lcnt[ln], 1);
      if (pos < ECAP) {
        lel[(ln << 6) + pos] = p.x;
      } else {                              // high-degree node: agg ovf fixup
        int o = atomicAdd(ovf_cnt, 1);
        if (o < OVF_CAP) { ovf[2 * o] = p.x; ovf[2 * o + 1] = p.y; }
      }
    }
  }
  __syncthreads();
  if (tid < BIN_NODES) {
    int n = n0 + tid;
    if (n < N_NODES) {
      int tot = cnt[n] + lcnt[tid];          // cnt[n]: pass-1 ovf edges only
      cnt[n] = tot;                          // safe: block owns node range
      dinv[n] = rsqrtf((float)tot + 1.0f);   // fused dinv
    }
  }
  int4* gel = (int4*)(elist + (size_t)n0 * ECAP);
  const int4* lel4 = (const int4*)lel;
  for (int i = tid; i < BIN_NODES * ECAP / 4; i += 256) gel[i] = lel4[i];
}

// ---------------- layer-2 GEMM: C(bf16) = relu(A(bf16)) @ W via MFMA ----------
__global__ __launch_bounds__(256) void gemm_bf16in_kernel(const unsigned short* __restrict__ A,
                                                          const unsigned short* __restrict__ Wt,
                                                          unsigned short* __restrict__ C) {
  int tid = threadIdx.x;
  int wave = tid >> 6, lane = tid & 63;
  int q = lane >> 4, r = lane & 15;
  int m0 = blockIdx.x * 64 + wave * 16;
  int arow = m0 + r; if (arow > N_NODES - 1) arow = N_NODES - 1;
  const unsigned short* Arow = A + (size_t)arow * NFEAT;

  f32x4 acc[8];
  #pragma unroll
  for (int t = 0; t < 8; ++t) acc[t] = (f32x4){0.f, 0.f, 0.f, 0.f};

  #pragma unroll
  for (int s = 0; s < 4; ++s) {
    int k0 = s * 32 + q * 8;
    bf16x8 xf = *(const bf16x8*)(Arow + k0);   // direct 16B bf16 load
    #pragma unroll
    for (int i = 0; i < 8; ++i)                // relu: bf16 sign bit == short sign
      xf[i] = (short)(xf[i] < (short)0 ? (short)0 : xf[i]);
    #pragma unroll
    for (int t = 0; t < 8; ++t) {
      bf16x8 wf = *(const bf16x8*)(Wt + (size_t)(t * 16 + r) * NFEAT + k0);
      acc[t] = __builtin_amdgcn_mfma_f32_16x16x32_bf16(wf, xf, acc[t], 0, 0, 0);
    }
  }
  int node = m0 + r;
  if (node < N_NODES) {
    uint2* Crow = (uint2*)(C + (size_t)node * NFEAT);
    #pragma unroll
    for (int t = 0; t < 8; ++t) {
      uint2 v;
      v.x = ((unsigned)f2bf(acc[t][1]) << 16) | f2bf(acc[t][0]);
      v.y = ((unsigned)f2bf(acc[t][3]) << 16) | f2bf(acc[t][2]);
      Crow[t * 4 + q] = v;
    }
  }
}

// ---------------- gather aggregation: HALF-WAVE per node (random-gather wall
// ~64us) + fused ovf fixup (fp32, pre-rounding) ----------
__global__ __launch_bounds__(256) void agg_kernel(const uint2* __restrict__ h2,
                                                  const int* __restrict__ elist,
                                                  const int* __restrict__ cnt,
                                                  const float* __restrict__ dinv,
                                                  const float* __restrict__ bias,
                                                  const int* __restrict__ ovf_cnt,
                                                  const int* __restrict__ ovf,
                                                  uint2* __restrict__ out) {
  int wid = (blockIdx.x * 256 + threadIdx.x) >> 6;
  int lane = threadIdx.x & 63;
  int hl = lane & 31;
  int n = wid * 2 + (lane >> 5);
  if (n >= N_NODES) return;
  float dn = dinv[n];
  int c = cnt[n]; c = (c > ECAP) ? ECAP : c;
  const int* el = elist + (size_t)n * ECAP;

  int   s0 = (hl < c)      ? el[hl]      : n;
  float w0 = (hl < c)      ? dinv[s0] * dn : 0.f;
  int   s1 = (hl + 32 < c) ? el[hl + 32] : n;
  float w1 = (hl + 32 < c) ? dinv[s1] * dn : 0.f;

  int cA = __shfl(c, 0), cB = __shfl(c, 32);
  int cmax = cA > cB ? cA : cB;

  uint2 hv = h2[(size_t)n * 32 + hl];
  float2 vlo = bfu2f(hv.x), vhi = bfu2f(hv.y);
  float sw = dn * dn;
  float a0 = sw * vlo.x, a1 = sw * vlo.y, a2 = sw * vhi.x, a3 = sw * vhi.y;

  int e1 = cmax < 32 ? cmax : 32;
  int j = 0;
  for (; j + 8 <= e1; j += 8) {
    uint2 pv[8]; float w[8];
    #pragma unroll
    for (int u = 0; u < 8; ++u) {
      int s = __shfl(s0, j + u, 32);
      w[u] = __shfl(w0, j + u, 32);
      pv[u] = h2[(size_t)s * 32 + hl];
    }
    #pragma unroll
    for (int u = 0; u < 8; ++u) {
      float2 lo = bfu2f(pv[u].x), hi = bfu2f(pv[u].y);
      a0 = fmaf(w[u], lo.x, a0); a1 = fmaf(w[u], lo.y, a1);
      a2 = fmaf(w[u], hi.x, a2); a3 = fmaf(w[u], hi.y, a3);
    }
  }
  for (; j < e1; ++j) {
    int s = __shfl(s0, j, 32);
    float w = __shfl(w0, j, 32);
    uint2 pv = h2[(size_t)s * 32 + hl];
    float2 lo = bfu2f(pv.x), hi = bfu2f(pv.y);
    a0 = fmaf(w, lo.x, a0); a1 = fmaf(w, lo.y, a1);
    a2 = fmaf(w, hi.x, a2); a3 = fmaf(w, hi.y, a3);
  }
  if (cmax > 32) {
    j = 32;
    for (; j + 8 <= cmax; j += 8) {
      uint2 pv[8]; float w[8];
      #pragma unroll
      for (int u = 0; u < 8; ++u) {
        int s = __shfl(s1, j - 32 + u, 32);
        w[u] = __shfl(w1, j - 32 + u, 32);
        pv[u] = h2[(size_t)s * 32 + hl];
      }
      #pragma unroll
      for (int u = 0; u < 8; ++u) {
        float2 lo = bfu2f(pv[u].x), hi = bfu2f(pv[u].y);
        a0 = fmaf(w[u], lo.x, a0); a1 = fmaf(w[u], lo.y, a1);
        a2 = fmaf(w[u], hi.x, a2); a3 = fmaf(w[u], hi.y, a3);
      }
    }
    for (; j < cmax; ++j) {
      int s = __shfl(s1, j - 32, 32);
      float w = __shfl(w1, j - 32, 32);
      uint2 pv = h2[(size_t)s * 32 + hl];
      float2 lo = bfu2f(pv.x), hi = bfu2f(pv.y);
      a0 = fmaf(w, lo.x, a0); a1 = fmaf(w, lo.y, a1);
      a2 = fmaf(w, hi.x, a2); a3 = fmaf(w, hi.y, a3);
    }
  }

  // ovf fixup in fp32 before rounding (m == 0 on this input: one load + exit)
  int m = *ovf_cnt; if (m > OVF_CAP) m = OVF_CAP;
  for (int p = 0; p < m; ++p) {
    int s = ovf[2 * p], d = ovf[2 * p + 1];
    if (d == n) {
      float w = dinv[s] * dn;
      uint2 pv = h2[(size_t)s * 32 + hl];
      float2 lo = bfu2f(pv.x), hi = bfu2f(pv.y);
      a0 = fmaf(w, lo.x, a0); a1 = fmaf(w, lo.y, a1);
      a2 = fmaf(w, hi.x, a2); a3 = fmaf(w, hi.y, a3);
    }
  }

  float4 b4 = ((const float4*)bias)[hl];
  uint2 r;
  r.x = ((unsigned)f2bf(a1 + b4.y) << 16) | f2bf(a0 + b4.x);
  r.y = ((unsigned)f2bf(a3 + b4.w) << 16) | f2bf(a2 + b4.z);
  out[(size_t)n * 32 + hl] = r;
}

// ---------------- pooled sum of relu(h) by (sorted) batch, h bf16 --------------
// R9 shape: 1563 blocks of 64 threads (parallelism >> 256-block fusion, R12 lesson)
#define PCHUNK 64
__global__ __launch_bounds__(64) void pool_kernel(const unsigned* __restrict__ hu,
                                                  const int* __restrict__ batch,
                                                  float* __restrict__ gsum) {
  int lane = threadIdx.x;
  int n0 = blockIdx.x * PCHUNK;
  if (n0 >= N_NODES) return;
  int n1 = n0 + PCHUNK; if (n1 > N_NODES) n1 = N_NODES;
  float ax = 0.f, ay = 0.f;
  int cur = batch[n0];
  for (int n = n0; n < n1; ++n) {
    int b = batch[n];
    if (b != cur) {
      atomicAdd(&gsum[cur * NFEAT + 2 * lane], ax);
      atomicAdd(&gsum[cur * NFEAT + 2 * lane + 1], ay);
      ax = 0.f; ay = 0.f; cur = b;
    }
    float2 v = bfu2f(hu[(size_t)n * 64 + lane]);
    ax += fmaxf(v.x, 0.f);
    ay += fmaxf(v.y, 0.f);
  }
  atomicAdd(&gsum[cur * NFEAT + 2 * lane], ax);
  atomicAdd(&gsum[cur * NFEAT + 2 * lane + 1], ay);
}

// ---------------- MLP head (graph-count binary search fused in) ----------------
__global__ __launch_bounds__(128) void mlp_kernel(const float* __restrict__ gsum,
                                                  const int* __restrict__ batch,
                                                  const float* __restrict__ Wl1,
                                                  const float* __restrict__ bl1,
                                                  const float* __restrict__ Wl2,
                                                  const float* __restrict__ bl2,
                                                  float* __restrict__ out) {
  __shared__ float gr[NFEAT];
  __shared__ float t1[NFEAT];
  __shared__ float sinv;
  int g = blockIdx.x, t = threadIdx.x;
  if (t == 0) {
    int lo = 0, hi = N_NODES;
    while (lo < hi) { int mid = (lo + hi) >> 1; if (batch[mid] < g) lo = mid + 1; else hi = mid; }
    int lo2 = lo, hi2 = N_NODES;
    while (lo2 < hi2) { int mid = (lo2 + hi2) >> 1; if (batch[mid] < g + 1) lo2 = mid + 1; else hi2 = mid; }
    sinv = 1.0f / fmaxf((float)(lo2 - lo), 1.0f);
  }
  __syncthreads();
  gr[t] = gsum[g * NFEAT + t] * sinv;
  __syncthreads();
  float acc = bl1[t];
  for (int k = 0; k < NFEAT; ++k) acc = fmaf(gr[k], Wl1[k * NFEAT + t], acc);
  t1[t] = fmaxf(acc, 0.f);
  __syncthreads();
  if (t < NACT) {
    float a2 = bl2[t];
    for (int k = 0; k < NFEAT; ++k) a2 = fmaf(t1[k], Wl2[k * NACT + t], a2);
    out[g * NACT + t] = a2;
  }
}

extern "C" void kernel_launch(void* const* d_in, const int* in_sizes, int n_in,
                              void* d_out, int out_size, void* d_ws, size_t ws_size,
                              hipStream_t stream) {
  const float* x    = (const float*)d_in[0];
  const int*   ei   = (const int*)d_in[1];
  const int*   batch= (const int*)d_in[2];
  const float* W1   = (const float*)d_in[3];
  const float* b1   = (const float*)d_in[4];
  const float* W2   = (const float*)d_in[5];
  const float* b2   = (const float*)d_in[6];
  const float* Wl1  = (const float*)d_in[7];
  const float* bl1  = (const float*)d_in[8];
  const float* Wl2  = (const float*)d_in[9];
  const float* bl2  = (const float*)d_in[10];
  float* out = (float*)d_out;

  const int* srcp = ei;            // edge_index[0]
  const int* dstp = ei + N_EDGES;  // edge_index[1]

  char* base = (char*)d_ws;
  size_t off = 0;
  auto alloc = [&](size_t bytes) -> void* {
    void* p = base + off;
    off += (bytes + 511) & ~(size_t)511;
    return p;
  };
  int*   cnt     = (int*)alloc((size_t)N_NODES * 4);
  int*   ovfc    = (int*)alloc(4);
  float* gsum    = (float*)alloc((size_t)NGRAPH * NFEAT * 4);
  int*   bucket_cursor = (int*)alloc((size_t)NBUCK * 4);
  size_t zspan   = off;  // everything above must start zeroed
  float* dinv    = (float*)alloc((size_t)N_NODES * 4);
  int*   elist   = (int*)alloc((size_t)NBLK2 * BIN_NODES * ECAP * 4); // padded
  int*   ovf     = (int*)alloc((size_t)OVF_CAP * 2 * 4);
  int2*  seg     = (int2*)alloc((size_t)NBUCK * SEGCAP * 8);          // 16 MB
  unsigned short* Wt1 = (unsigned short*)alloc((size_t)NFEAT * NFEAT * 2);
  unsigned short* Wt2 = (unsigned short*)alloc((size_t)NFEAT * NFEAT * 2);
  unsigned short* A = (unsigned short*)alloc((size_t)N_NODES * NFEAT * 2); // bf16
  unsigned short* B = (unsigned short*)alloc((size_t)N_NODES * NFEAT * 2); // bf16

  hipMemsetAsync(d_ws, 0, zspan, stream);

  const int AB = (N_NODES + 7) / 8;       // 12500 agg blocks (8 nodes/block)

  // L1: edge partition UNION weight transpose (independent)
  edgepart_wt_kernel<<<NBLK1 + WTBLK, 256, 0, stream>>>(
      srcp, dstp, bucket_cursor, seg, cnt, ovfc, ovf, W1, W2, Wt1, Wt2);
  // L2: elist build UNION layer-1 GEMM (independent; both dep on L1)
  binbuild_gemm_kernel<<<NBLK2 + GB, 256, 0, stream>>>(
      seg, bucket_cursor, cnt, dinv, elist, ovfc, ovf, x, Wt1, A);
  // L3: layer-1 aggregation (+fused ovf fixup)
  agg_kernel<<<AB, 256, 0, stream>>>((const uint2*)A, elist, cnt, dinv, b1, ovfc, ovf, (uint2*)B);
  // L4: layer-2 GEMM (relu fused on load)
  gemm_bf16in_kernel<<<GB, 256, 0, stream>>>(B, Wt2, A);
  // L5: layer-2 aggregation
  agg_kernel<<<AB, 256, 0, stream>>>((const uint2*)A, elist, cnt, dinv, b2, ovfc, ovf, (uint2*)B);
  // L6/L7: pool + head
  pool_kernel<<<(N_NODES + PCHUNK - 1) / PCHUNK, 64, 0, stream>>>((const unsigned*)B, batch, gsum);
  mlp_kernel<<<NGRAPH, 128, 0, stream>>>(gsum, batch, Wl1, bl1, Wl2, bl2, out);
}

// Round 14
// 341.335 us; speedup vs baseline: 1.1593x; 1.0608x over previous
//
#include <hip/hip_runtime.h>
#include <hip/hip_bf16.h>

#define N_NODES 100000
#define N_EDGES 1600000
#define NFEAT   128
#define NGRAPH  256
#define NACT    32
#define ECAP    64
#define OVF_CAP 8192

// ---- two-pass edge partition ----
#define BUCK_SHIFT 9
#define BUCK_NODES 512
#define NBUCK ((N_NODES + BUCK_NODES - 1) / BUCK_NODES)   // 196
#define SEGCAP 10240          // mean 8192, +22 sigma
#define CHUNK 4096            // edges per pass-1 block (R9-measured best)
#define NBLK1 ((N_EDGES + CHUNK - 1) / CHUNK)             // 391
#define BIN_NODES 128         // pass-2 nodes per block
#define NBLK2 ((N_NODES + BIN_NODES - 1) / BIN_NODES)     // 782
#define GB ((N_NODES + 63) / 64)                          // 1563 gemm blocks
#define WTBLK (2 * NFEAT * NFEAT / 256)                   // 128 wt blocks

typedef __attribute__((ext_vector_type(8))) short bf16x8;
typedef __attribute__((ext_vector_type(4))) float f32x4;

__device__ inline unsigned short f2bf(float f) {
  __hip_bfloat16 b = __float2bfloat16(f);
  return *reinterpret_cast<unsigned short*>(&b);
}
__device__ inline float2 bfu2f(unsigned u) {
  __hip_bfloat162 t = *reinterpret_cast<__hip_bfloat162*>(&u);
  return __bfloat1622float2(t);
}

// ---- launch 1: edgepart (blocks [0,NBLK1)) UNION wt transpose (rest) ----
__global__ __launch_bounds__(256) void edgepart_wt_kernel(const int* __restrict__ src,
                                                          const int* __restrict__ dst,
                                                          int* __restrict__ bucket_cursor,
                                                          int2* __restrict__ seg,
                                                          int* __restrict__ cnt,
                                                          int* __restrict__ ovf_cnt,
                                                          int* __restrict__ ovf,
                                                          const float* __restrict__ W1,
                                                          const float* __restrict__ W2,
                                                          unsigned short* __restrict__ Wt1,
                                                          unsigned short* __restrict__ Wt2) {
  __shared__ int2 stage[CHUNK];               // 32 KB
  __shared__ int hist[NBUCK], offs[NBUCK], cursor[NBUCK], gbase[NBUCK];
  __shared__ int sc[256];
  int tid = threadIdx.x;

  if (blockIdx.x >= NBLK1) {                  // ---- wt transpose part ----
    int i = (blockIdx.x - NBLK1) * 256 + tid; // 32768 weight elems
    int which = i >> 14;
    int idx = i & 16383;
    int n = idx >> 7, k = idx & 127;
    if (which == 0) Wt1[n * NFEAT + k] = f2bf(W1[k * NFEAT + n]);
    else            Wt2[n * NFEAT + k] = f2bf(W2[k * NFEAT + n]);
    return;
  }

  // ---- edgepart part ----
  int e0 = blockIdx.x * CHUNK;
  int m = N_EDGES - e0; if (m > CHUNK) m = CHUNK;

  for (int i = tid; i < NBUCK; i += 256) hist[i] = 0;
  __syncthreads();

  for (int i = tid; i < m; i += 256)
    atomicAdd(&hist[dst[e0 + i] >> BUCK_SHIFT], 1);
  __syncthreads();

  sc[tid] = (tid < NBUCK) ? hist[tid] : 0;
  __syncthreads();
  for (int ofs = 1; ofs < 256; ofs <<= 1) {
    int t = (tid >= ofs) ? sc[tid - ofs] : 0;
    __syncthreads();
    sc[tid] += t;
    __syncthreads();
  }
  if (tid < NBUCK) {
    int o = tid ? sc[tid - 1] : 0;
    offs[tid] = o;
    cursor[tid] = o;
    gbase[tid] = hist[tid] ? atomicAdd(&bucket_cursor[tid], hist[tid]) : 0;
  }
  __syncthreads();

  for (int i = tid; i < m; i += 256) {
    int2 p = make_int2(src[e0 + i], dst[e0 + i]);
    int pos = atomicAdd(&cursor[p.y >> BUCK_SHIFT], 1);
    stage[pos] = p;
  }
  __syncthreads();

  for (int i = tid; i < m; i += 256) {
    int2 p = stage[i];
    int bd = p.y >> BUCK_SHIFT;
    int gpos = gbase[bd] + (i - offs[bd]);
    if (gpos < SEGCAP) {
      seg[(size_t)bd * SEGCAP + gpos] = p;
    } else {                                // ~never: count + defer to agg ovf fixup
      atomicAdd(&cnt[p.y], 1);
      int o = atomicAdd(ovf_cnt, 1);
      if (o < OVF_CAP) { ovf[2 * o] = p.x; ovf[2 * o + 1] = p.y; }
    }
  }
}

// ---- launch 2: binbuild (blocks [0,NBLK2)) UNION layer-1 GEMM (rest) ----
__global__ __launch_bounds__(256) void binbuild_gemm_kernel(const int2* __restrict__ seg,
                                                            const int* __restrict__ bucket_cursor,
                                                            int* __restrict__ cnt,
                                                            float* __restrict__ dinv,
                                                            int* __restrict__ elist,
                                                            int* __restrict__ ovf_cnt,
                                                            int* __restrict__ ovf,
                                                            const float* __restrict__ x,
                                                            const unsigned short* __restrict__ Wt,
                                                            unsigned short* __restrict__ C) {
  __shared__ int lcnt[BIN_NODES];
  __shared__ int lel[BIN_NODES * ECAP];     // 32 KB
  int tid = threadIdx.x;

  if (blockIdx.x >= NBLK2) {                // ---- gemm1: C(bf16) = x(f32) @ W1 ----
    int bid = blockIdx.x - NBLK2;
    int wave = tid >> 6, lane = tid & 63;
    int q = lane >> 4, r = lane & 15;
    int m0 = bid * 64 + wave * 16;
    int arow = m0 + r; if (arow > N_NODES - 1) arow = N_NODES - 1;
    const float* Arow = x + (size_t)arow * NFEAT;

    f32x4 acc[8];
    #pragma unroll
    for (int t = 0; t < 8; ++t) acc[t] = (f32x4){0.f, 0.f, 0.f, 0.f};

    #pragma unroll
    for (int s = 0; s < 4; ++s) {
      int k0 = s * 32 + q * 8;
      float4 a0 = *(const float4*)(Arow + k0);
      float4 a1 = *(const float4*)(Arow + k0 + 4);
      bf16x8 xf;
      xf[0] = (short)f2bf(a0.x); xf[1] = (short)f2bf(a0.y);
      xf[2] = (short)f2bf(a0.z); xf[3] = (short)f2bf(a0.w);
      xf[4] = (short)f2bf(a1.x); xf[5] = (short)f2bf(a1.y);
      xf[6] = (short)f2bf(a1.z); xf[7] = (short)f2bf(a1.w);
      #pragma unroll
      for (int t = 0; t < 8; ++t) {
        bf16x8 wf = *(const bf16x8*)(Wt + (size_t)(t * 16 + r) * NFEAT + k0);
        acc[t] = __builtin_amdgcn_mfma_f32_16x16x32_bf16(wf, xf, acc[t], 0, 0, 0);
      }
    }
    int node = m0 + r;
    if (node < N_NODES) {
      uint2* Crow = (uint2*)(C + (size_t)node * NFEAT);
      #pragma unroll
      for (int t = 0; t < 8; ++t) {
        uint2 v;
        v.x = ((unsigned)f2bf(acc[t][1]) << 16) | f2bf(acc[t][0]);
        v.y = ((unsigned)f2bf(acc[t][3]) << 16) | f2bf(acc[t][2]);
        Crow[t * 4 + q] = v;    // features [t*16+q*4, +4)
      }
    }
    return;
  }

  // ---- binbuild part ----
  int n0 = blockIdx.x * BIN_NODES;
  int pb = n0 >> BUCK_SHIFT;
  if (tid < BIN_NODES) lcnt[tid] = 0;
  __syncthreads();
  int m = bucket_cursor[pb]; if (m > SEGCAP) m = SEGCAP;
  const int2* s = seg + (size_t)pb * SEGCAP;
  for (int e = tid; e < m; e += 256) {
    int2 p = s[e];
    unsigned ln = (unsigned)(p.y - n0);
    if (ln < (unsigned)BIN_NODES) {
      int pos = atomicAdd(&lcnt[ln], 1);
      if (pos < ECAP) {
        lel[(ln << 6) + pos] = p.x;
      } else {                              // high-degree node: agg ovf fixup
        int o = atomicAdd(ovf_cnt, 1);
        if (o < OVF_CAP) { ovf[2 * o] = p.x; ovf[2 * o + 1] = p.y; }
      }
    }
  }
  __syncthreads();
  if (tid < BIN_NODES) {
    int n = n0 + tid;
    if (n < N_NODES) {
      int tot = cnt[n] + lcnt[tid];          // cnt[n]: pass-1 ovf edges only
      cnt[n] = tot;                          // safe: block owns node range
      dinv[n] = rsqrtf((float)tot + 1.0f);   // fused dinv
    }
  }
  int4* gel = (int4*)(elist + (size_t)n0 * ECAP);
  const int4* lel4 = (const int4*)lel;
  for (int i = tid; i < BIN_NODES * ECAP / 4; i += 256) gel[i] = lel4[i];
}

// ---------------- layer-2 GEMM: C(bf16) = relu(A(bf16)) @ W via MFMA ----------
__global__ __launch_bounds__(256) void gemm_bf16in_kernel(const unsigned short* __restrict__ A,
                                                          const unsigned short* __restrict__ Wt,
                                                          unsigned short* __restrict__ C) {
  int tid = threadIdx.x;
  int wave = tid >> 6, lane = tid & 63;
  int q = lane >> 4, r = lane & 15;
  int m0 = blockIdx.x * 64 + wave * 16;
  int arow = m0 + r; if (arow > N_NODES - 1) arow = N_NODES - 1;
  const unsigned short* Arow = A + (size_t)arow * NFEAT;

  f32x4 acc[8];
  #pragma unroll
  for (int t = 0; t < 8; ++t) acc[t] = (f32x4){0.f, 0.f, 0.f, 0.f};

  #pragma unroll
  for (int s = 0; s < 4; ++s) {
    int k0 = s * 32 + q * 8;
    bf16x8 xf = *(const bf16x8*)(Arow + k0);   // direct 16B bf16 load
    #pragma unroll
    for (int i = 0; i < 8; ++i)                // relu: bf16 sign bit == short sign
      xf[i] = (short)(xf[i] < (short)0 ? (short)0 : xf[i]);
    #pragma unroll
    for (int t = 0; t < 8; ++t) {
      bf16x8 wf = *(const bf16x8*)(Wt + (size_t)(t * 16 + r) * NFEAT + k0);
      acc[t] = __builtin_amdgcn_mfma_f32_16x16x32_bf16(wf, xf, acc[t], 0, 0, 0);
    }
  }
  int node = m0 + r;
  if (node < N_NODES) {
    uint2* Crow = (uint2*)(C + (size_t)node * NFEAT);
    #pragma unroll
    for (int t = 0; t < 8; ++t) {
      uint2 v;
      v.x = ((unsigned)f2bf(acc[t][1]) << 16) | f2bf(acc[t][0]);
      v.y = ((unsigned)f2bf(acc[t][3]) << 16) | f2bf(acc[t][2]);
      Crow[t * 4 + q] = v;
    }
  }
}

// ---------------- layer-1 aggregation: HALF-WAVE per node (random-gather wall
// ~64us) + fused ovf fixup (fp32, pre-rounding); writes bf16 B ----------
__global__ __launch_bounds__(256) void agg_kernel(const uint2* __restrict__ h2,
                                                  const int* __restrict__ elist,
                                                  const int* __restrict__ cnt,
                                                  const float* __restrict__ dinv,
                                                  const float* __restrict__ bias,
                                                  const int* __restrict__ ovf_cnt,
                                                  const int* __restrict__ ovf,
                                                  uint2* __restrict__ out) {
  int wid = (blockIdx.x * 256 + threadIdx.x) >> 6;
  int lane = threadIdx.x & 63;
  int hl = lane & 31;
  int n = wid * 2 + (lane >> 5);
  if (n >= N_NODES) return;
  float dn = dinv[n];
  int c = cnt[n]; c = (c > ECAP) ? ECAP : c;
  const int* el = elist + (size_t)n * ECAP;

  int   s0 = (hl < c)      ? el[hl]      : n;
  float w0 = (hl < c)      ? dinv[s0] * dn : 0.f;
  int   s1 = (hl + 32 < c) ? el[hl + 32] : n;
  float w1 = (hl + 32 < c) ? dinv[s1] * dn : 0.f;

  int cA = __shfl(c, 0), cB = __shfl(c, 32);
  int cmax = cA > cB ? cA : cB;

  uint2 hv = h2[(size_t)n * 32 + hl];
  float2 vlo = bfu2f(hv.x), vhi = bfu2f(hv.y);
  float sw = dn * dn;
  float a0 = sw * vlo.x, a1 = sw * vlo.y, a2 = sw * vhi.x, a3 = sw * vhi.y;

  int e1 = cmax < 32 ? cmax : 32;
  int j = 0;
  for (; j + 8 <= e1; j += 8) {
    uint2 pv[8]; float w[8];
    #pragma unroll
    for (int u = 0; u < 8; ++u) {
      int s = __shfl(s0, j + u, 32);
      w[u] = __shfl(w0, j + u, 32);
      pv[u] = h2[(size_t)s * 32 + hl];
    }
    #pragma unroll
    for (int u = 0; u < 8; ++u) {
      float2 lo = bfu2f(pv[u].x), hi = bfu2f(pv[u].y);
      a0 = fmaf(w[u], lo.x, a0); a1 = fmaf(w[u], lo.y, a1);
      a2 = fmaf(w[u], hi.x, a2); a3 = fmaf(w[u], hi.y, a3);
    }
  }
  for (; j < e1; ++j) {
    int s = __shfl(s0, j, 32);
    float w = __shfl(w0, j, 32);
    uint2 pv = h2[(size_t)s * 32 + hl];
    float2 lo = bfu2f(pv.x), hi = bfu2f(pv.y);
    a0 = fmaf(w, lo.x, a0); a1 = fmaf(w, lo.y, a1);
    a2 = fmaf(w, hi.x, a2); a3 = fmaf(w, hi.y, a3);
  }
  if (cmax > 32) {
    j = 32;
    for (; j + 8 <= cmax; j += 8) {
      uint2 pv[8]; float w[8];
      #pragma unroll
      for (int u = 0; u < 8; ++u) {
        int s = __shfl(s1, j - 32 + u, 32);
        w[u] = __shfl(w1, j - 32 + u, 32);
        pv[u] = h2[(size_t)s * 32 + hl];
      }
      #pragma unroll
      for (int u = 0; u < 8; ++u) {
        float2 lo = bfu2f(pv[u].x), hi = bfu2f(pv[u].y);
        a0 = fmaf(w[u], lo.x, a0); a1 = fmaf(w[u], lo.y, a1);
        a2 = fmaf(w[u], hi.x, a2); a3 = fmaf(w[u], hi.y, a3);
      }
    }
    for (; j < cmax; ++j) {
      int s = __shfl(s1, j - 32, 32);
      float w = __shfl(w1, j - 32, 32);
      uint2 pv = h2[(size_t)s * 32 + hl];
      float2 lo = bfu2f(pv.x), hi = bfu2f(pv.y);
      a0 = fmaf(w, lo.x, a0); a1 = fmaf(w, lo.y, a1);
      a2 = fmaf(w, hi.x, a2); a3 = fmaf(w, hi.y, a3);
    }
  }

  int m = *ovf_cnt; if (m > OVF_CAP) m = OVF_CAP;
  for (int p = 0; p < m; ++p) {
    int s = ovf[2 * p], d = ovf[2 * p + 1];
    if (d == n) {
      float w = dinv[s] * dn;
      uint2 pv = h2[(size_t)s * 32 + hl];
      float2 lo = bfu2f(pv.x), hi = bfu2f(pv.y);
      a0 = fmaf(w, lo.x, a0); a1 = fmaf(w, lo.y, a1);
      a2 = fmaf(w, hi.x, a2); a3 = fmaf(w, hi.y, a3);
    }
  }

  float4 b4 = ((const float4*)bias)[hl];
  uint2 r;
  r.x = ((unsigned)f2bf(a1 + b4.y) << 16) | f2bf(a0 + b4.x);
  r.y = ((unsigned)f2bf(a3 + b4.w) << 16) | f2bf(a2 + b4.z);
  out[(size_t)n * 32 + hl] = r;
}

// ---------------- layer-2 aggregation + FUSED POOL ----------------
// Same gather loop, but instead of writing B: relu the fp32 accumulators
// (pre-rounding, more exact), stage block's 8 nodes x 128 feats in LDS, then
// per-feature run-length reduce over sorted batch -> ~1.1x128 atomics/block.
__global__ __launch_bounds__(256) void agg_pool_kernel(const uint2* __restrict__ h2,
                                                       const int* __restrict__ elist,
                                                       const int* __restrict__ cnt,
                                                       const float* __restrict__ dinv,
                                                       const float* __restrict__ bias,
                                                       const int* __restrict__ ovf_cnt,
                                                       const int* __restrict__ ovf,
                                                       const int* __restrict__ batch,
                                                       float* __restrict__ gsum) {
  __shared__ float lds[8][NFEAT];            // 4 KB
  int tid = threadIdx.x;
  int wid = (blockIdx.x * 256 + tid) >> 6;
  int lane = tid & 63;
  int hl = lane & 31;
  int n = wid * 2 + (lane >> 5);             // grid covers exactly N_NODES (12500*8)
  int n0 = blockIdx.x * 8;

  float dn = dinv[n];
  int c = cnt[n]; c = (c > ECAP) ? ECAP : c;
  const int* el = elist + (size_t)n * ECAP;

  int   s0 = (hl < c)      ? el[hl]      : n;
  float w0 = (hl < c)      ? dinv[s0] * dn : 0.f;
  int   s1 = (hl + 32 < c) ? el[hl + 32] : n;
  float w1 = (hl + 32 < c) ? dinv[s1] * dn : 0.f;

  int cA = __shfl(c, 0), cB = __shfl(c, 32);
  int cmax = cA > cB ? cA : cB;

  uint2 hv = h2[(size_t)n * 32 + hl];
  float2 vlo = bfu2f(hv.x), vhi = bfu2f(hv.y);
  float sw = dn * dn;
  float a0 = sw * vlo.x, a1 = sw * vlo.y, a2 = sw * vhi.x, a3 = sw * vhi.y;

  int e1 = cmax < 32 ? cmax : 32;
  int j = 0;
  for (; j + 8 <= e1; j += 8) {
    uint2 pv[8]; float w[8];
    #pragma unroll
    for (int u = 0; u < 8; ++u) {
      int s = __shfl(s0, j + u, 32);
      w[u] = __shfl(w0, j + u, 32);
      pv[u] = h2[(size_t)s * 32 + hl];
    }
    #pragma unroll
    for (int u = 0; u < 8; ++u) {
      float2 lo = bfu2f(pv[u].x), hi = bfu2f(pv[u].y);
      a0 = fmaf(w[u], lo.x, a0); a1 = fmaf(w[u], lo.y, a1);
      a2 = fmaf(w[u], hi.x, a2); a3 = fmaf(w[u], hi.y, a3);
    }
  }
  for (; j < e1; ++j) {
    int s = __shfl(s0, j, 32);
    float w = __shfl(w0, j, 32);
    uint2 pv = h2[(size_t)s * 32 + hl];
    float2 lo = bfu2f(pv.x), hi = bfu2f(pv.y);
    a0 = fmaf(w, lo.x, a0); a1 = fmaf(w, lo.y, a1);
    a2 = fmaf(w, hi.x, a2); a3 = fmaf(w, hi.y, a3);
  }
  if (cmax > 32) {
    j = 32;
    for (; j + 8 <= cmax; j += 8) {
      uint2 pv[8]; float w[8];
      #pragma unroll
      for (int u = 0; u < 8; ++u) {
        int s = __shfl(s1, j - 32 + u, 32);
        w[u] = __shfl(w1, j - 32 + u, 32);
        pv[u] = h2[(size_t)s * 32 + hl];
      }
      #pragma unroll
      for (int u = 0; u < 8; ++u) {
        float2 lo = bfu2f(pv[u].x), hi = bfu2f(pv[u].y);
        a0 = fmaf(w[u], lo.x, a0); a1 = fmaf(w[u], lo.y, a1);
        a2 = fmaf(w[u], hi.x, a2); a3 = fmaf(w[u], hi.y, a3);
      }
    }
    for (; j < cmax; ++j) {
      int s = __shfl(s1, j - 32, 32);
      float w = __shfl(w1, j - 32, 32);
      uint2 pv = h2[(size_t)s * 32 + hl];
      float2 lo = bfu2f(pv.x), hi = bfu2f(pv.y);
      a0 = fmaf(w, lo.x, a0); a1 = fmaf(w, lo.y, a1);
      a2 = fmaf(w, hi.x, a2); a3 = fmaf(w, hi.y, a3);
    }
  }

  int m = *ovf_cnt; if (m > OVF_CAP) m = OVF_CAP;
  for (int p = 0; p < m; ++p) {
    int s = ovf[2 * p], d = ovf[2 * p + 1];
    if (d == n) {
      float w = dinv[s] * dn;
      uint2 pv = h2[(size_t)s * 32 + hl];
      float2 lo = bfu2f(pv.x), hi = bfu2f(pv.y);
      a0 = fmaf(w, lo.x, a0); a1 = fmaf(w, lo.y, a1);
      a2 = fmaf(w, hi.x, a2); a3 = fmaf(w, hi.y, a3);
    }
  }

  float4 b4 = ((const float4*)bias)[hl];
  int nloc = n - n0;
  lds[nloc][hl * 4 + 0] = fmaxf(a0 + b4.x, 0.f);
  lds[nloc][hl * 4 + 1] = fmaxf(a1 + b4.y, 0.f);
  lds[nloc][hl * 4 + 2] = fmaxf(a2 + b4.z, 0.f);
  lds[nloc][hl * 4 + 3] = fmaxf(a3 + b4.w, 0.f);
  __syncthreads();

  if (tid < NFEAT) {                         // thread t = feature t
    float sum = 0.f;
    int cur = batch[n0];
    #pragma unroll
    for (int i = 0; i < 8; ++i) {
      int b = batch[n0 + i];                 // L2-hot, wave-uniform-ish
      if (b != cur) {
        atomicAdd(&gsum[cur * NFEAT + tid], sum);
        sum = 0.f; cur = b;
      }
      sum += lds[i][tid];
    }
    atomicAdd(&gsum[cur * NFEAT + tid], sum);
  }
}

// ---------------- MLP head (graph-count binary search fused in) ----------------
__global__ __launch_bounds__(128) void mlp_kernel(const float* __restrict__ gsum,
                                                  const int* __restrict__ batch,
                                                  const float* __restrict__ Wl1,
                                                  const float* __restrict__ bl1,
                                                  const float* __restrict__ Wl2,
                                                  const float* __restrict__ bl2,
                                                  float* __restrict__ out) {
  __shared__ float gr[NFEAT];
  __shared__ float t1[NFEAT];
  __shared__ float sinv;
  int g = blockIdx.x, t = threadIdx.x;
  if (t == 0) {
    int lo = 0, hi = N_NODES;
    while (lo < hi) { int mid = (lo + hi) >> 1; if (batch[mid] < g) lo = mid + 1; else hi = mid; }
    int lo2 = lo, hi2 = N_NODES;
    while (lo2 < hi2) { int mid = (lo2 + hi2) >> 1; if (batch[mid] < g + 1) lo2 = mid + 1; else hi2 = mid; }
    sinv = 1.0f / fmaxf((float)(lo2 - lo), 1.0f);
  }
  __syncthreads();
  gr[t] = gsum[g * NFEAT + t] * sinv;
  __syncthreads();
  float acc = bl1[t];
  for (int k = 0; k < NFEAT; ++k) acc = fmaf(gr[k], Wl1[k * NFEAT + t], acc);
  t1[t] = fmaxf(acc, 0.f);
  __syncthreads();
  if (t < NACT) {
    float a2 = bl2[t];
    for (int k = 0; k < NFEAT; ++k) a2 = fmaf(t1[k], Wl2[k * NACT + t], a2);
    out[g * NACT + t] = a2;
  }
}

extern "C" void kernel_launch(void* const* d_in, const int* in_sizes, int n_in,
                              void* d_out, int out_size, void* d_ws, size_t ws_size,
                              hipStream_t stream) {
  const float* x    = (const float*)d_in[0];
  const int*   ei   = (const int*)d_in[1];
  const int*   batch= (const int*)d_in[2];
  const float* W1   = (const float*)d_in[3];
  const float* b1   = (const float*)d_in[4];
  const float* W2   = (const float*)d_in[5];
  const float* b2   = (const float*)d_in[6];
  const float* Wl1  = (const float*)d_in[7];
  const float* bl1  = (const float*)d_in[8];
  const float* Wl2  = (const float*)d_in[9];
  const float* bl2  = (const float*)d_in[10];
  float* out = (float*)d_out;

  const int* srcp = ei;            // edge_index[0]
  const int* dstp = ei + N_EDGES;  // edge_index[1]

  char* base = (char*)d_ws;
  size_t off = 0;
  auto alloc = [&](size_t bytes) -> void* {
    void* p = base + off;
    off += (bytes + 511) & ~(size_t)511;
    return p;
  };
  int*   cnt     = (int*)alloc((size_t)N_NODES * 4);
  int*   ovfc    = (int*)alloc(4);
  float* gsum    = (float*)alloc((size_t)NGRAPH * NFEAT * 4);
  int*   bucket_cursor = (int*)alloc((size_t)NBUCK * 4);
  size_t zspan   = off;  // everything above must start zeroed
  float* dinv    = (float*)alloc((size_t)N_NODES * 4);
  int*   elist   = (int*)alloc((size_t)NBLK2 * BIN_NODES * ECAP * 4); // padded
  int*   ovf     = (int*)alloc((size_t)OVF_CAP * 2 * 4);
  int2*  seg     = (int2*)alloc((size_t)NBUCK * SEGCAP * 8);          // 16 MB
  unsigned short* Wt1 = (unsigned short*)alloc((size_t)NFEAT * NFEAT * 2);
  unsigned short* Wt2 = (unsigned short*)alloc((size_t)NFEAT * NFEAT * 2);
  unsigned short* A = (unsigned short*)alloc((size_t)N_NODES * NFEAT * 2); // bf16
  unsigned short* B = (unsigned short*)alloc((size_t)N_NODES * NFEAT * 2); // bf16

  hipMemsetAsync(d_ws, 0, zspan, stream);

  const int AB = (N_NODES + 7) / 8;       // 12500 agg blocks (8 nodes/block)

  // L1: edge partition UNION weight transpose (independent)
  edgepart_wt_kernel<<<NBLK1 + WTBLK, 256, 0, stream>>>(
      srcp, dstp, bucket_cursor, seg, cnt, ovfc, ovf, W1, W2, Wt1, Wt2);
  // L2: elist build UNION layer-1 GEMM (independent; both dep on L1)
  binbuild_gemm_kernel<<<NBLK2 + GB, 256, 0, stream>>>(
      seg, bucket_cursor, cnt, dinv, elist, ovfc, ovf, x, Wt1, A);
  // L3: layer-1 aggregation (+fused ovf fixup)
  agg_kernel<<<AB, 256, 0, stream>>>((const uint2*)A, elist, cnt, dinv, b1, ovfc, ovf, (uint2*)B);
  // L4: layer-2 GEMM (relu fused on load)
  gemm_bf16in_kernel<<<GB, 256, 0, stream>>>(B, Wt2, A);
  // L5: layer-2 aggregation + fused pool (no B write)
  agg_pool_kernel<<<AB, 256, 0, stream>>>((const uint2*)A, elist, cnt, dinv, b2, ovfc, ovf,
                                          batch, gsum);
  // L6: head
  mlp_kernel<<<NGRAPH, 128, 0, stream>>>(gsum, batch, Wl1, bl1, Wl2, bl2, out);
}

// Round 15
// 327.068 us; speedup vs baseline: 1.2098x; 1.0436x over previous
//
#include <hip/hip_runtime.h>
#include <hip/hip_bf16.h>

#define N_NODES 100000
#define N_EDGES 1600000
#define NFEAT   128
#define NGRAPH  256
#define NACT    32
#define ECAP    64
#define OVF_CAP 8192

// ---- two-pass edge partition ----
#define BUCK_SHIFT 9
#define BUCK_NODES 512
#define NBUCK ((N_NODES + BUCK_NODES - 1) / BUCK_NODES)   // 196
#define SEGCAP 10240          // mean 8192, +22 sigma
#define CHUNK 4096            // edges per pass-1 block (R9-measured best)
#define NBLK1 ((N_EDGES + CHUNK - 1) / CHUNK)             // 391
#define BIN_NODES 128         // pass-2 nodes per block
#define NBLK2 ((N_NODES + BIN_NODES - 1) / BIN_NODES)     // 782
#define GB ((N_NODES + 63) / 64)                          // 1563 gemm blocks
#define WTBLK (2 * NFEAT * NFEAT / 256)                   // 128 wt blocks
#define LDSROW 136            // ushort row stride: 16B-aligned, uniform banks

typedef __attribute__((ext_vector_type(8))) short bf16x8;
typedef __attribute__((ext_vector_type(4))) float f32x4;

__device__ inline unsigned short f2bf(float f) {
  __hip_bfloat16 b = __float2bfloat16(f);
  return *reinterpret_cast<unsigned short*>(&b);
}
__device__ inline float2 bfu2f(unsigned u) {
  __hip_bfloat162 t = *reinterpret_cast<__hip_bfloat162*>(&u);
  return __bfloat1622float2(t);
}

// ---- launch 1: edgepart (blocks [0,NBLK1)) UNION wt transpose (rest) ----
__global__ __launch_bounds__(256) void edgepart_wt_kernel(const int* __restrict__ src,
                                                          const int* __restrict__ dst,
                                                          int* __restrict__ bucket_cursor,
                                                          int2* __restrict__ seg,
                                                          int* __restrict__ cnt,
                                                          int* __restrict__ ovf_cnt,
                                                          int* __restrict__ ovf,
                                                          const float* __restrict__ W1,
                                                          const float* __restrict__ W2,
                                                          unsigned short* __restrict__ Wt1,
                                                          unsigned short* __restrict__ Wt2) {
  __shared__ int2 stage[CHUNK];               // 32 KB
  __shared__ int hist[NBUCK], offs[NBUCK], cursor[NBUCK], gbase[NBUCK];
  __shared__ int sc[256];
  int tid = threadIdx.x;

  if (blockIdx.x >= NBLK1) {                  // ---- wt transpose part ----
    int i = (blockIdx.x - NBLK1) * 256 + tid; // 32768 weight elems
    int which = i >> 14;
    int idx = i & 16383;
    int n = idx >> 7, k = idx & 127;
    if (which == 0) Wt1[n * NFEAT + k] = f2bf(W1[k * NFEAT + n]);
    else            Wt2[n * NFEAT + k] = f2bf(W2[k * NFEAT + n]);
    return;
  }

  // ---- edgepart part ----
  int e0 = blockIdx.x * CHUNK;
  int m = N_EDGES - e0; if (m > CHUNK) m = CHUNK;

  for (int i = tid; i < NBUCK; i += 256) hist[i] = 0;
  __syncthreads();

  for (int i = tid; i < m; i += 256)
    atomicAdd(&hist[dst[e0 + i] >> BUCK_SHIFT], 1);
  __syncthreads();

  sc[tid] = (tid < NBUCK) ? hist[tid] : 0;
  __syncthreads();
  for (int ofs = 1; ofs < 256; ofs <<= 1) {
    int t = (tid >= ofs) ? sc[tid - ofs] : 0;
    __syncthreads();
    sc[tid] += t;
    __syncthreads();
  }
  if (tid < NBUCK) {
    int o = tid ? sc[tid - 1] : 0;
    offs[tid] = o;
    cursor[tid] = o;
    gbase[tid] = hist[tid] ? atomicAdd(&bucket_cursor[tid], hist[tid]) : 0;
  }
  __syncthreads();

  for (int i = tid; i < m; i += 256) {
    int2 p = make_int2(src[e0 + i], dst[e0 + i]);
    int pos = atomicAdd(&cursor[p.y >> BUCK_SHIFT], 1);
    stage[pos] = p;
  }
  __syncthreads();

  for (int i = tid; i < m; i += 256) {
    int2 p = stage[i];
    int bd = p.y >> BUCK_SHIFT;
    int gpos = gbase[bd] + (i - offs[bd]);
    if (gpos < SEGCAP) {
      seg[(size_t)bd * SEGCAP + gpos] = p;
    } else {                                // ~never: count + defer to agg ovf fixup
      atomicAdd(&cnt[p.y], 1);
      int o = atomicAdd(ovf_cnt, 1);
      if (o < OVF_CAP) { ovf[2 * o] = p.x; ovf[2 * o + 1] = p.y; }
    }
  }
}

// ---- launch 2: binbuild (blocks [0,NBLK2)) UNION layer-1 GEMM (rest) ----
__global__ __launch_bounds__(256) void binbuild_gemm_kernel(const int2* __restrict__ seg,
                                                            const int* __restrict__ bucket_cursor,
                                                            int* __restrict__ cnt,
                                                            float* __restrict__ dinv,
                                                            int* __restrict__ elist,
                                                            int* __restrict__ ovf_cnt,
                                                            int* __restrict__ ovf,
                                                            const float* __restrict__ x,
                                                            const unsigned short* __restrict__ Wt,
                                                            unsigned short* __restrict__ C) {
  __shared__ int lcnt[BIN_NODES];
  __shared__ int lel[BIN_NODES * ECAP];     // 32 KB
  int tid = threadIdx.x;

  if (blockIdx.x >= NBLK2) {                // ---- gemm1: C(bf16) = x(f32) @ W1 ----
    int bid = blockIdx.x - NBLK2;
    int wave = tid >> 6, lane = tid & 63;
    int q = lane >> 4, r = lane & 15;
    int m0 = bid * 64 + wave * 16;
    int arow = m0 + r; if (arow > N_NODES - 1) arow = N_NODES - 1;
    const float* Arow = x + (size_t)arow * NFEAT;

    f32x4 acc[8];
    #pragma unroll
    for (int t = 0; t < 8; ++t) acc[t] = (f32x4){0.f, 0.f, 0.f, 0.f};

    #pragma unroll
    for (int s = 0; s < 4; ++s) {
      int k0 = s * 32 + q * 8;
      float4 a0 = *(const float4*)(Arow + k0);
      float4 a1 = *(const float4*)(Arow + k0 + 4);
      bf16x8 xf;
      xf[0] = (short)f2bf(a0.x); xf[1] = (short)f2bf(a0.y);
      xf[2] = (short)f2bf(a0.z); xf[3] = (short)f2bf(a0.w);
      xf[4] = (short)f2bf(a1.x); xf[5] = (short)f2bf(a1.y);
      xf[6] = (short)f2bf(a1.z); xf[7] = (short)f2bf(a1.w);
      #pragma unroll
      for (int t = 0; t < 8; ++t) {
        bf16x8 wf = *(const bf16x8*)(Wt + (size_t)(t * 16 + r) * NFEAT + k0);
        acc[t] = __builtin_amdgcn_mfma_f32_16x16x32_bf16(wf, xf, acc[t], 0, 0, 0);
      }
    }
    int node = m0 + r;
    if (node < N_NODES) {
      uint2* Crow = (uint2*)(C + (size_t)node * NFEAT);
      #pragma unroll
      for (int t = 0; t < 8; ++t) {
        uint2 v;
        v.x = ((unsigned)f2bf(acc[t][1]) << 16) | f2bf(acc[t][0]);
        v.y = ((unsigned)f2bf(acc[t][3]) << 16) | f2bf(acc[t][2]);
        Crow[t * 4 + q] = v;    // features [t*16+q*4, +4)
      }
    }
    return;
  }

  // ---- binbuild part ----
  int n0 = blockIdx.x * BIN_NODES;
  int pb = n0 >> BUCK_SHIFT;
  if (tid < BIN_NODES) lcnt[tid] = 0;
  __syncthreads();
  int m = bucket_cursor[pb]; if (m > SEGCAP) m = SEGCAP;
  const int2* s = seg + (size_t)pb * SEGCAP;
  for (int e = tid; e < m; e += 256) {
    int2 p = s[e];
    unsigned ln = (unsigned)(p.y - n0);
    if (ln < (unsigned)BIN_NODES) {
      int pos = atomicAdd(&lcnt[ln], 1);
      if (pos < ECAP) {
        lel[(ln << 6) + pos] = p.x;
      } else {                              // high-degree node: agg ovf fixup
        int o = atomicAdd(ovf_cnt, 1);
        if (o < OVF_CAP) { ovf[2 * o] = p.x; ovf[2 * o + 1] = p.y; }
      }
    }
  }
  __syncthreads();
  if (tid < BIN_NODES) {
    int n = n0 + tid;
    if (n < N_NODES) {
      int tot = cnt[n] + lcnt[tid];          // cnt[n]: pass-1 ovf edges only
      cnt[n] = tot;                          // safe: block owns node range
      dinv[n] = rsqrtf((float)tot + 1.0f);   // fused dinv
    }
  }
  int4* gel = (int4*)(elist + (size_t)n0 * ECAP);
  const int4* lel4 = (const int4*)lel;
  for (int i = tid; i < BIN_NODES * ECAP / 4; i += 256) gel[i] = lel4[i];
}

// ---------------- launch 3: layer-1 aggregation FUSED with layer-2 GEMM ------
// 512 threads = 8 waves = 16 nodes/block (half-wave gather per node).
// Phase 1: gather -> fp32 acc -> +bias, relu (fp32, pre-round) -> bf16 LDS tile.
// Phase 2: wave w computes output feature block w via 4 MFMAs from the LDS
// tile + L2-hot Wt2; coalesced uint2 epilogue (verified layout). Saves the
// 25MB B-write + 25.6MB B-read + one launch vs separate agg1 + gemm2.
__global__ __launch_bounds__(512) void agg_gemm_kernel(const uint2* __restrict__ h2,
                                                       const int* __restrict__ elist,
                                                       const int* __restrict__ cnt,
                                                       const float* __restrict__ dinv,
                                                       const float* __restrict__ bias,
                                                       const int* __restrict__ ovf_cnt,
                                                       const int* __restrict__ ovf,
                                                       const unsigned short* __restrict__ Wt2,
                                                       unsigned short* __restrict__ H2) {
  __shared__ __align__(16) unsigned short hloc[16 * LDSROW];  // 4.25 KB
  int tid = threadIdx.x;
  int lane = tid & 63;
  int lw = tid >> 6;                         // local wave 0..7
  int hl = lane & 31;
  int n0 = blockIdx.x * 16;
  int nloc = lw * 2 + (lane >> 5);
  int n = n0 + nloc;                         // grid exact: 6250*16 == N_NODES

  float dn = dinv[n];
  int c = cnt[n]; c = (c > ECAP) ? ECAP : c;
  const int* el = elist + (size_t)n * ECAP;

  int   s0 = (hl < c)      ? el[hl]      : n;
  float w0 = (hl < c)      ? dinv[s0] * dn : 0.f;
  int   s1 = (hl + 32 < c) ? el[hl + 32] : n;
  float w1 = (hl + 32 < c) ? dinv[s1] * dn : 0.f;

  int cA = __shfl(c, (lw << 6) & 63), cB;    // c is uniform per half-wave already
  cA = __shfl(c, 0);  cB = __shfl(c, 32);
  int cmax = cA > cB ? cA : cB;

  uint2 hv = h2[(size_t)n * 32 + hl];
  float2 vlo = bfu2f(hv.x), vhi = bfu2f(hv.y);
  float sw = dn * dn;
  float a0 = sw * vlo.x, a1 = sw * vlo.y, a2 = sw * vhi.x, a3 = sw * vhi.y;

  int e1 = cmax < 32 ? cmax : 32;
  int j = 0;
  for (; j + 8 <= e1; j += 8) {
    uint2 pv[8]; float w[8];
    #pragma unroll
    for (int u = 0; u < 8; ++u) {
      int s = __shfl(s0, j + u, 32);
      w[u] = __shfl(w0, j + u, 32);
      pv[u] = h2[(size_t)s * 32 + hl];
    }
    #pragma unroll
    for (int u = 0; u < 8; ++u) {
      float2 lo = bfu2f(pv[u].x), hi = bfu2f(pv[u].y);
      a0 = fmaf(w[u], lo.x, a0); a1 = fmaf(w[u], lo.y, a1);
      a2 = fmaf(w[u], hi.x, a2); a3 = fmaf(w[u], hi.y, a3);
    }
  }
  for (; j < e1; ++j) {
    int s = __shfl(s0, j, 32);
    float w = __shfl(w0, j, 32);
    uint2 pv = h2[(size_t)s * 32 + hl];
    float2 lo = bfu2f(pv.x), hi = bfu2f(pv.y);
    a0 = fmaf(w, lo.x, a0); a1 = fmaf(w, lo.y, a1);
    a2 = fmaf(w, hi.x, a2); a3 = fmaf(w, hi.y, a3);
  }
  if (cmax > 32) {
    j = 32;
    for (; j + 8 <= cmax; j += 8) {
      uint2 pv[8]; float w[8];
      #pragma unroll
      for (int u = 0; u < 8; ++u) {
        int s = __shfl(s1, j - 32 + u, 32);
        w[u] = __shfl(w1, j - 32 + u, 32);
        pv[u] = h2[(size_t)s * 32 + hl];
      }
      #pragma unroll
      for (int u = 0; u < 8; ++u) {
        float2 lo = bfu2f(pv[u].x), hi = bfu2f(pv[u].y);
        a0 = fmaf(w[u], lo.x, a0); a1 = fmaf(w[u], lo.y, a1);
        a2 = fmaf(w[u], hi.x, a2); a3 = fmaf(w[u], hi.y, a3);
      }
    }
    for (; j < cmax; ++j) {
      int s = __shfl(s1, j - 32, 32);
      float w = __shfl(w1, j - 32, 32);
      uint2 pv = h2[(size_t)s * 32 + hl];
      float2 lo = bfu2f(pv.x), hi = bfu2f(pv.y);
      a0 = fmaf(w, lo.x, a0); a1 = fmaf(w, lo.y, a1);
      a2 = fmaf(w, hi.x, a2); a3 = fmaf(w, hi.y, a3);
    }
  }

  int m = *ovf_cnt; if (m > OVF_CAP) m = OVF_CAP;
  for (int p = 0; p < m; ++p) {
    int s = ovf[2 * p], d = ovf[2 * p + 1];
    if (d == n) {
      float w = dinv[s] * dn;
      uint2 pv = h2[(size_t)s * 32 + hl];
      float2 lo = bfu2f(pv.x), hi = bfu2f(pv.y);
      a0 = fmaf(w, lo.x, a0); a1 = fmaf(w, lo.y, a1);
      a2 = fmaf(w, hi.x, a2); a3 = fmaf(w, hi.y, a3);
    }
  }

  float4 b4 = ((const float4*)bias)[hl];
  uint2 v;
  v.x = ((unsigned)f2bf(fmaxf(a1 + b4.y, 0.f)) << 16) | f2bf(fmaxf(a0 + b4.x, 0.f));
  v.y = ((unsigned)f2bf(fmaxf(a3 + b4.w, 0.f)) << 16) | f2bf(fmaxf(a2 + b4.z, 0.f));
  *(uint2*)(&hloc[nloc * LDSROW + hl * 4]) = v;
  __syncthreads();

  // ---- phase 2: gemm2 tile. wave lw -> output feats [lw*16, lw*16+16) ----
  int q = lane >> 4, r = lane & 15;
  f32x4 acc = (f32x4){0.f, 0.f, 0.f, 0.f};
  #pragma unroll
  for (int s = 0; s < 4; ++s) {
    int k0 = s * 32 + q * 8;
    bf16x8 xf = *(const bf16x8*)(&hloc[r * LDSROW + k0]);
    bf16x8 wf = *(const bf16x8*)(Wt2 + (size_t)(lw * 16 + r) * NFEAT + k0);
    acc = __builtin_amdgcn_mfma_f32_16x16x32_bf16(wf, xf, acc, 0, 0, 0);
  }
  int node = n0 + r;
  uint2* Crow = (uint2*)(H2 + (size_t)node * NFEAT);
  uint2 o;
  o.x = ((unsigned)f2bf(acc[1]) << 16) | f2bf(acc[0]);
  o.y = ((unsigned)f2bf(acc[3]) << 16) | f2bf(acc[2]);
  Crow[lw * 4 + q] = o;                      // feats [lw*16+q*4, +4)
}

// ---------------- launch 4: layer-2 aggregation + FUSED POOL ----------------
__global__ __launch_bounds__(256) void agg_pool_kernel(const uint2* __restrict__ h2,
                                                       const int* __restrict__ elist,
                                                       const int* __restrict__ cnt,
                                                       const float* __restrict__ dinv,
                                                       const float* __restrict__ bias,
                                                       const int* __restrict__ ovf_cnt,
                                                       const int* __restrict__ ovf,
                                                       const int* __restrict__ batch,
                                                       float* __restrict__ gsum) {
  __shared__ float lds[8][NFEAT];            // 4 KB
  int tid = threadIdx.x;
  int wid = (blockIdx.x * 256 + tid) >> 6;
  int lane = tid & 63;
  int hl = lane & 31;
  int n = wid * 2 + (lane >> 5);             // grid covers exactly N_NODES
  int n0 = blockIdx.x * 8;

  float dn = dinv[n];
  int c = cnt[n]; c = (c > ECAP) ? ECAP : c;
  const int* el = elist + (size_t)n * ECAP;

  int   s0 = (hl < c)      ? el[hl]      : n;
  float w0 = (hl < c)      ? dinv[s0] * dn : 0.f;
  int   s1 = (hl + 32 < c) ? el[hl + 32] : n;
  float w1 = (hl + 32 < c) ? dinv[s1] * dn : 0.f;

  int cA = __shfl(c, 0), cB = __shfl(c, 32);
  int cmax = cA > cB ? cA : cB;

  uint2 hv = h2[(size_t)n * 32 + hl];
  float2 vlo = bfu2f(hv.x), vhi = bfu2f(hv.y);
  float sw = dn * dn;
  float a0 = sw * vlo.x, a1 = sw * vlo.y, a2 = sw * vhi.x, a3 = sw * vhi.y;

  int e1 = cmax < 32 ? cmax : 32;
  int j = 0;
  for (; j + 8 <= e1; j += 8) {
    uint2 pv[8]; float w[8];
    #pragma unroll
    for (int u = 0; u < 8; ++u) {
      int s = __shfl(s0, j + u, 32);
      w[u] = __shfl(w0, j + u, 32);
      pv[u] = h2[(size_t)s * 32 + hl];
    }
    #pragma unroll
    for (int u = 0; u < 8; ++u) {
      float2 lo = bfu2f(pv[u].x), hi = bfu2f(pv[u].y);
      a0 = fmaf(w[u], lo.x, a0); a1 = fmaf(w[u], lo.y, a1);
      a2 = fmaf(w[u], hi.x, a2); a3 = fmaf(w[u], hi.y, a3);
    }
  }
  for (; j < e1; ++j) {
    int s = __shfl(s0, j, 32);
    float w = __shfl(w0, j, 32);
    uint2 pv = h2[(size_t)s * 32 + hl];
    float2 lo = bfu2f(pv.x), hi = bfu2f(pv.y);
    a0 = fmaf(w, lo.x, a0); a1 = fmaf(w, lo.y, a1);
    a2 = fmaf(w, hi.x, a2); a3 = fmaf(w, hi.y, a3);
  }
  if (cmax > 32) {
    j = 32;
    for (; j + 8 <= cmax; j += 8) {
      uint2 pv[8]; float w[8];
      #pragma unroll
      for (int u = 0; u < 8; ++u) {
        int s = __shfl(s1, j - 32 + u, 32);
        w[u] = __shfl(w1, j - 32 + u, 32);
        pv[u] = h2[(size_t)s * 32 + hl];
      }
      #pragma unroll
      for (int u = 0; u < 8; ++u) {
        float2 lo = bfu2f(pv[u].x), hi = bfu2f(pv[u].y);
        a0 = fmaf(w[u], lo.x, a0); a1 = fmaf(w[u], lo.y, a1);
        a2 = fmaf(w[u], hi.x, a2); a3 = fmaf(w[u], hi.y, a3);
      }
    }
    for (; j < cmax; ++j) {
      int s = __shfl(s1, j - 32, 32);
      float w = __shfl(w1, j - 32, 32);
      uint2 pv = h2[(size_t)s * 32 + hl];
      float2 lo = bfu2f(pv.x), hi = bfu2f(pv.y);
      a0 = fmaf(w, lo.x, a0); a1 = fmaf(w, lo.y, a1);
      a2 = fmaf(w, hi.x, a2); a3 = fmaf(w, hi.y, a3);
    }
  }

  int m = *ovf_cnt; if (m > OVF_CAP) m = OVF_CAP;
  for (int p = 0; p < m; ++p) {
    int s = ovf[2 * p], d = ovf[2 * p + 1];
    if (d == n) {
      float w = dinv[s] * dn;
      uint2 pv = h2[(size_t)s * 32 + hl];
      float2 lo = bfu2f(pv.x), hi = bfu2f(pv.y);
      a0 = fmaf(w, lo.x, a0); a1 = fmaf(w, lo.y, a1);
      a2 = fmaf(w, hi.x, a2); a3 = fmaf(w, hi.y, a3);
    }
  }

  float4 b4 = ((const float4*)bias)[hl];
  int nloc = n - n0;
  lds[nloc][hl * 4 + 0] = fmaxf(a0 + b4.x, 0.f);
  lds[nloc][hl * 4 + 1] = fmaxf(a1 + b4.y, 0.f);
  lds[nloc][hl * 4 + 2] = fmaxf(a2 + b4.z, 0.f);
  lds[nloc][hl * 4 + 3] = fmaxf(a3 + b4.w, 0.f);
  __syncthreads();

  if (tid < NFEAT) {                         // thread t = feature t
    float sum = 0.f;
    int cur = batch[n0];
    #pragma unroll
    for (int i = 0; i < 8; ++i) {
      int b = batch[n0 + i];
      if (b != cur) {
        atomicAdd(&gsum[cur * NFEAT + tid], sum);
        sum = 0.f; cur = b;
      }
      sum += lds[i][tid];
    }
    atomicAdd(&gsum[cur * NFEAT + tid], sum);
  }
}

// ---------------- MLP head (graph-count binary search fused in) ----------------
__global__ __launch_bounds__(128) void mlp_kernel(const float* __restrict__ gsum,
                                                  const int* __restrict__ batch,
                                                  const float* __restrict__ Wl1,
                                                  const float* __restrict__ bl1,
                                                  const float* __restrict__ Wl2,
                                                  const float* __restrict__ bl2,
                                                  float* __restrict__ out) {
  __shared__ float gr[NFEAT];
  __shared__ float t1[NFEAT];
  __shared__ float sinv;
  int g = blockIdx.x, t = threadIdx.x;
  if (t == 0) {
    int lo = 0, hi = N_NODES;
    while (lo < hi) { int mid = (lo + hi) >> 1; if (batch[mid] < g) lo = mid + 1; else hi = mid; }
    int lo2 = lo, hi2 = N_NODES;
    while (lo2 < hi2) { int mid = (lo2 + hi2) >> 1; if (batch[mid] < g + 1) lo2 = mid + 1; else hi2 = mid; }
    sinv = 1.0f / fmaxf((float)(lo2 - lo), 1.0f);
  }
  __syncthreads();
  gr[t] = gsum[g * NFEAT + t] * sinv;
  __syncthreads();
  float acc = bl1[t];
  for (int k = 0; k < NFEAT; ++k) acc = fmaf(gr[k], Wl1[k * NFEAT + t], acc);
  t1[t] = fmaxf(acc, 0.f);
  __syncthreads();
  if (t < NACT) {
    float a2 = bl2[t];
    for (int k = 0; k < NFEAT; ++k) a2 = fmaf(t1[k], Wl2[k * NACT + t], a2);
    out[g * NACT + t] = a2;
  }
}

extern "C" void kernel_launch(void* const* d_in, const int* in_sizes, int n_in,
                              void* d_out, int out_size, void* d_ws, size_t ws_size,
                              hipStream_t stream) {
  const float* x    = (const float*)d_in[0];
  const int*   ei   = (const int*)d_in[1];
  const int*   batch= (const int*)d_in[2];
  const float* W1   = (const float*)d_in[3];
  const float* b1   = (const float*)d_in[4];
  const float* W2   = (const float*)d_in[5];
  const float* b2   = (const float*)d_in[6];
  const float* Wl1  = (const float*)d_in[7];
  const float* bl1  = (const float*)d_in[8];
  const float* Wl2  = (const float*)d_in[9];
  const float* bl2  = (const float*)d_in[10];
  float* out = (float*)d_out;

  const int* srcp = ei;            // edge_index[0]
  const int* dstp = ei + N_EDGES;  // edge_index[1]

  char* base = (char*)d_ws;
  size_t off = 0;
  auto alloc = [&](size_t bytes) -> void* {
    void* p = base + off;
    off += (bytes + 511) & ~(size_t)511;
    return p;
  };
  int*   cnt     = (int*)alloc((size_t)N_NODES * 4);
  int*   ovfc    = (int*)alloc(4);
  float* gsum    = (float*)alloc((size_t)NGRAPH * NFEAT * 4);
  int*   bucket_cursor = (int*)alloc((size_t)NBUCK * 4);
  size_t zspan   = off;  // everything above must start zeroed
  float* dinv    = (float*)alloc((size_t)N_NODES * 4);
  int*   elist   = (int*)alloc((size_t)NBLK2 * BIN_NODES * ECAP * 4); // padded
  int*   ovf     = (int*)alloc((size_t)OVF_CAP * 2 * 4);
  int2*  seg     = (int2*)alloc((size_t)NBUCK * SEGCAP * 8);          // 16 MB
  unsigned short* Wt1 = (unsigned short*)alloc((size_t)NFEAT * NFEAT * 2);
  unsigned short* Wt2 = (unsigned short*)alloc((size_t)NFEAT * NFEAT * 2);
  unsigned short* H1 = (unsigned short*)alloc((size_t)N_NODES * NFEAT * 2); // bf16
  unsigned short* H2 = (unsigned short*)alloc((size_t)N_NODES * NFEAT * 2); // bf16

  hipMemsetAsync(d_ws, 0, zspan, stream);

  const int AB = (N_NODES + 7) / 8;       // 12500 agg_pool blocks (8 nodes/block)
  const int FB = N_NODES / 16;            // 6250 fused agg+gemm blocks (16 nodes)

  // L1: edge partition UNION weight transpose (independent)
  edgepart_wt_kernel<<<NBLK1 + WTBLK, 256, 0, stream>>>(
      srcp, dstp, bucket_cursor, seg, cnt, ovfc, ovf, W1, W2, Wt1, Wt2);
  // L2: elist build UNION layer-1 GEMM (independent; both dep on L1)
  binbuild_gemm_kernel<<<NBLK2 + GB, 256, 0, stream>>>(
      seg, bucket_cursor, cnt, dinv, elist, ovfc, ovf, x, Wt1, H1);
  // L3: layer-1 aggregation FUSED with layer-2 GEMM (no intermediate buffer)
  agg_gemm_kernel<<<FB, 512, 0, stream>>>((const uint2*)H1, elist, cnt, dinv, b1,
                                          ovfc, ovf, Wt2, H2);
  // L4: layer-2 aggregation + fused pool
  agg_pool_kernel<<<AB, 256, 0, stream>>>((const uint2*)H2, elist, cnt, dinv, b2,
                                          ovfc, ovf, batch, gsum);
  // L5: head
  mlp_kernel<<<NGRAPH, 128, 0, stream>>>(gsum, batch, Wl1, bl1, Wl2, bl2, out);
}